// Round 1
// baseline (2347.922 us; speedup 1.0000x reference)
//
#include <hip/hip_runtime.h>
#include <math.h>

// Problem constants (also derived from in_sizes at runtime where cheap)
#define HDIM 32
#define NHEAD 8
#define DMODEL 256
#define NTYPE 4
#define ETYPE 3
#define NLAYER 3

// ---------------------------------------------------------------------------
// CSR build kernels (edge structure is layer-invariant; built once per launch)
// ---------------------------------------------------------------------------
__global__ void count_deg_kernel(const int* __restrict__ dst, int* __restrict__ deg, int E) {
  int tid = blockIdx.x * 256 + threadIdx.x;
  if (tid < E) atomicAdd(&deg[dst[tid]], 1);
}

__global__ __launch_bounds__(1024) void scan_kernel(const int* __restrict__ deg,
                                                    int* __restrict__ off, int n) {
  __shared__ int part[1024];
  int t = threadIdx.x;
  int chunk = (n + 1023) >> 10;
  int base = t * chunk;
  int s = 0;
  for (int i = 0; i < chunk; ++i) {
    int idx = base + i;
    if (idx < n) s += deg[idx];
  }
  part[t] = s;
  __syncthreads();
  for (int o = 1; o < 1024; o <<= 1) {
    int v = (t >= o) ? part[t - o] : 0;
    __syncthreads();
    part[t] += v;
    __syncthreads();
  }
  int run = part[t] - s;  // exclusive prefix for this chunk
  for (int i = 0; i < chunk; ++i) {
    int idx = base + i;
    if (idx < n) { off[idx] = run; run += deg[idx]; }
  }
  if (t == 1023) off[n] = part[1023];
}

__global__ void scatter_kernel(const int* __restrict__ dst, const int* __restrict__ off,
                               int* __restrict__ cursor, int* __restrict__ csr, int E) {
  int tid = blockIdx.x * 256 + threadIdx.x;
  if (tid < E) {
    int d = dst[tid];
    int p = atomicAdd(&cursor[d], 1);
    csr[off[d] + p] = tid;
  }
}

// ---------------------------------------------------------------------------
// Per-node typed transforms: Q, V, and K-tilde (K pre-transformed by all edge
// types) — avoids the per-edge K@W_E matmul entirely.
// ---------------------------------------------------------------------------
__global__ __launch_bounds__(256) void qkv_kernel(
    const float* __restrict__ x, const int* __restrict__ node_type,
    const float* __restrict__ WQ, const float* __restrict__ WK,
    const float* __restrict__ WV, const float* __restrict__ WE,
    float* __restrict__ Q, float* __restrict__ V, float* __restrict__ Kt) {
  int n = blockIdx.x;
  int t = threadIdx.x;
  int h = t >> 5, e = t & 31;
  __shared__ float xs[256];
  __shared__ float ks[256];
  xs[t] = x[(size_t)n * 256 + t];
  __syncthreads();
  int nt = node_type[n];
  const float* xh = &xs[h * 32];
  const float* wq = WQ + ((size_t)nt * NHEAD + h) * 1024;
  const float* wk = WK + ((size_t)nt * NHEAD + h) * 1024;
  const float* wv = WV + ((size_t)nt * NHEAD + h) * 1024;
  float qa = 0.f, ka = 0.f, va = 0.f;
#pragma unroll
  for (int d = 0; d < 32; ++d) {
    float xv = xh[d];
    qa += xv * wq[d * 32 + e];
    ka += xv * wk[d * 32 + e];
    va += xv * wv[d * 32 + e];
  }
  Q[(size_t)n * 256 + t] = qa;
  V[(size_t)n * 256 + t] = va;
  ks[t] = ka;
  __syncthreads();
  const float* kh = &ks[h * 32];
  for (int et = 0; et < ETYPE; ++et) {
    const float* we = WE + ((size_t)et * NHEAD + h) * 1024;
    float a = 0.f;
#pragma unroll
    for (int d = 0; d < 32; ++d) a += kh[d] * we[d * 32 + e];
    Kt[(size_t)n * (ETYPE * 256) + et * 256 + t] = a;
  }
}

// ---------------------------------------------------------------------------
// Edge scores: score[e,h] = <Q[dst,h,:], Ktilde[src,et,h,:]> / sqrt(HD) * mu
// ---------------------------------------------------------------------------
__global__ __launch_bounds__(256) void score_kernel(
    const int* __restrict__ src, const int* __restrict__ dst,
    const int* __restrict__ etype, const float* __restrict__ Q,
    const float* __restrict__ Kt, const float* __restrict__ mu,
    float* __restrict__ scores, int E) {
  int tid = blockIdx.x * 256 + threadIdx.x;
  if (tid >= E * NHEAD) return;
  int eid = tid >> 3, h = tid & 7;
  int s = src[eid], d = dst[eid], t = etype[eid];
  const float4* q = (const float4*)(Q + (size_t)d * 256 + h * 32);
  const float4* k = (const float4*)(Kt + ((size_t)s * ETYPE + t) * 256 + h * 32);
  float acc = 0.f;
#pragma unroll
  for (int i = 0; i < 8; ++i) {
    float4 a = q[i], b = k[i];
    acc += a.x * b.x + a.y * b.y + a.z * b.z + a.w * b.w;
  }
  // 1/sqrt(32)
  scores[tid] = acc * 0.17677669529663687f * mu[h * ETYPE + t];
}

// ---------------------------------------------------------------------------
// Per-dst segment softmax + weighted V aggregation (CSR, no atomics)
// ---------------------------------------------------------------------------
__global__ __launch_bounds__(256) void agg_kernel(
    const int* __restrict__ off, const int* __restrict__ csr,
    const int* __restrict__ src, const float* __restrict__ scores,
    const float* __restrict__ V, float* __restrict__ agg) {
  int n = blockIdx.x;
  int t = threadIdx.x;
  int h = t >> 5, j = t & 31;
  int s0 = off[n], s1 = off[n + 1];
  float m = -1e9f;
  for (int k = s0 + j; k < s1; k += 32) {
    int e = csr[k];
    m = fmaxf(m, scores[(size_t)e * 8 + h]);
  }
  for (int o = 16; o > 0; o >>= 1) m = fmaxf(m, __shfl_xor(m, o, 32));
  float ssum = 0.f;
  for (int k = s0 + j; k < s1; k += 32) {
    int e = csr[k];
    ssum += expf(scores[(size_t)e * 8 + h] - m);
  }
  for (int o = 16; o > 0; o >>= 1) ssum += __shfl_xor(ssum, o, 32);
  float inv = 1.f / (ssum + 1e-10f);
  float acc = 0.f;
  for (int k = s0; k < s1; ++k) {
    int e = csr[k];
    float w = expf(scores[(size_t)e * 8 + h] - m) * inv;  // broadcast over j lanes
    int sn = src[e];
    acc += w * V[(size_t)sn * 256 + h * 32 + j];
  }
  agg[(size_t)n * 256 + t] = acc;
}

// ---------------------------------------------------------------------------
// fp32 tiled GEMM: C[M,Nc] = A[M,K] @ B[K,Nc] + bias, optional exact GELU.
// BM=BN=64, BK=16, 256 threads, 4x4 microtile, +4 LDS pad (16B-aligned, 2-way
// conflicts only which are free on gfx950).
// ---------------------------------------------------------------------------
template <int EPI>  // 0: bias only; 1: bias + exact gelu
__global__ __launch_bounds__(256) void gemm_kernel(
    const float* __restrict__ A, const float* __restrict__ B,
    const float* __restrict__ bias, float* __restrict__ C,
    int M, int K, int Nc) {
  __shared__ float As[16][68];
  __shared__ float Bs[16][68];
  const int t = threadIdx.x;
  const int row0 = blockIdx.y * 64;
  const int col0 = blockIdx.x * 64;
  const int la_r = t >> 2;         // 0..63
  const int la_k = (t & 3) * 4;    // 0,4,8,12
  const int lb_k = t >> 4;         // 0..15
  const int lb_n = (t & 15) * 4;   // 0..60
  const int tm = (t >> 4) * 4;
  const int tn = (t & 15) * 4;
  float acc[4][4] = {};
  for (int k0 = 0; k0 < K; k0 += 16) {
    float4 a4 = make_float4(0.f, 0.f, 0.f, 0.f);
    int ar = row0 + la_r;
    if (ar < M) a4 = *(const float4*)(A + (size_t)ar * K + k0 + la_k);
    As[la_k + 0][la_r] = a4.x;
    As[la_k + 1][la_r] = a4.y;
    As[la_k + 2][la_r] = a4.z;
    As[la_k + 3][la_r] = a4.w;
    *(float4*)&Bs[lb_k][lb_n] =
        *(const float4*)(B + (size_t)(k0 + lb_k) * Nc + col0 + lb_n);
    __syncthreads();
#pragma unroll
    for (int k = 0; k < 16; ++k) {
      float4 av = *(const float4*)&As[k][tm];
      float4 bv = *(const float4*)&Bs[k][tn];
      float aa[4] = {av.x, av.y, av.z, av.w};
      float bb[4] = {bv.x, bv.y, bv.z, bv.w};
#pragma unroll
      for (int i = 0; i < 4; ++i)
#pragma unroll
        for (int j = 0; j < 4; ++j) acc[i][j] += aa[i] * bb[j];
    }
    __syncthreads();
  }
#pragma unroll
  for (int i = 0; i < 4; ++i) {
    int r = row0 + tm + i;
    if (r >= M) continue;
    float4 o;
    float* op = &o.x;
#pragma unroll
    for (int j = 0; j < 4; ++j) {
      float v = acc[i][j] + bias[col0 + tn + j];
      if (EPI == 1) v = 0.5f * v * (1.f + erff(v * 0.70710678118654752f));
      op[j] = v;
    }
    *(float4*)(C + (size_t)r * Nc + col0 + tn) = o;
  }
}

// ---------------------------------------------------------------------------
// LayerNorm over rows of 256: out = LN(xin + res) * g + b   (res may be null)
// ---------------------------------------------------------------------------
__global__ __launch_bounds__(256) void ln_kernel(
    const float* __restrict__ xin, const float* __restrict__ res,
    const float* __restrict__ g, const float* __restrict__ b,
    float* __restrict__ out) {
  int n = blockIdx.x;
  int t = threadIdx.x;
  __shared__ float red[8];
  size_t idx = (size_t)n * 256 + t;
  float r = xin[idx] + (res ? res[idx] : 0.f);
  float s = r;
  for (int o = 32; o > 0; o >>= 1) s += __shfl_xor(s, o, 64);
  if ((t & 63) == 0) red[t >> 6] = s;
  __syncthreads();
  float m = (red[0] + red[1] + red[2] + red[3]) * (1.f / 256.f);
  float d = r - m;
  float s2 = d * d;
  for (int o = 32; o > 0; o >>= 1) s2 += __shfl_xor(s2, o, 64);
  if ((t & 63) == 0) red[4 + (t >> 6)] = s2;
  __syncthreads();
  float var = (red[4] + red[5] + red[6] + red[7]) * (1.f / 256.f);
  out[idx] = d * rsqrtf(var + 1e-5f) * g[t] + b[t];
}

// ---------------------------------------------------------------------------
extern "C" void kernel_launch(void* const* d_in, const int* in_sizes, int n_in,
                              void* d_out, int out_size, void* d_ws, size_t ws_size,
                              hipStream_t stream) {
  const float* x_in   = (const float*)d_in[0];
  const int*   ei     = (const int*)d_in[1];
  const int*   etype  = (const int*)d_in[2];
  const int*   ntype  = (const int*)d_in[3];
  const float* W_Q    = (const float*)d_in[4];
  const float* W_K    = (const float*)d_in[5];
  const float* W_V    = (const float*)d_in[6];
  const float* W_E    = (const float*)d_in[7];
  const float* mu     = (const float*)d_in[8];
  const float* Wo     = (const float*)d_in[9];
  const float* bo     = (const float*)d_in[10];
  const float* ln1g   = (const float*)d_in[11];
  const float* ln1b   = (const float*)d_in[12];
  const float* ln2g   = (const float*)d_in[13];
  const float* ln2b   = (const float*)d_in[14];
  const float* w1     = (const float*)d_in[15];
  const float* b1     = (const float*)d_in[16];
  const float* w2     = (const float*)d_in[17];
  const float* b2     = (const float*)d_in[18];
  const float* outg   = (const float*)d_in[19];
  const float* outb   = (const float*)d_in[20];

  const int N = in_sizes[0] / DMODEL;    // 20000
  const int E = in_sizes[1] / 2;         // 320000
  const int* src = ei;
  const int* dst = ei + E;

  const size_t NF = (size_t)N * DMODEL;  // floats per [N,256] buffer
  const size_t EH = (size_t)E * NHEAD;

  float* f      = (float*)d_ws;
  float* xbuf   = f;                 // NF
  float* Q      = f + NF;            // NF   (dead after score_kernel)
  float* V      = f + 2 * NF;        // NF   (dead after agg_kernel)
  float* Kt     = f + 3 * NF;        // 3*NF (dead after score_kernel)
  float* h1     = f + NF;            // 4*NF, aliases Q/V/Kt (all dead by then)
  float* scores = f + 6 * NF;        // EH
  float* agg    = f + 6 * NF + EH;   // NF
  float* fout   = agg + NF;          // NF
  int* ip       = (int*)(fout + NF);
  int* off      = ip;                // N+1
  int* csr      = ip + (N + 1);      // E
  int* cursor   = csr + E;           // N (doubles as deg)

  // ---- CSR build (once; structure is layer-invariant) ----
  hipMemsetAsync(cursor, 0, (size_t)N * sizeof(int), stream);
  count_deg_kernel<<<(E + 255) / 256, 256, 0, stream>>>(dst, cursor, E);
  scan_kernel<<<1, 1024, 0, stream>>>(cursor, off, N);
  hipMemsetAsync(cursor, 0, (size_t)N * sizeof(int), stream);
  scatter_kernel<<<(E + 255) / 256, 256, 0, stream>>>(dst, off, cursor, csr, E);

  // ---- x working copy ----
  hipMemcpyAsync(xbuf, x_in, NF * sizeof(float), hipMemcpyDeviceToDevice, stream);

  const int gm = (N + 63) / 64;
  for (int l = 0; l < NLAYER; ++l) {
    const float* WQl = W_Q + (size_t)l * NTYPE * NHEAD * 1024;
    const float* WKl = W_K + (size_t)l * NTYPE * NHEAD * 1024;
    const float* WVl = W_V + (size_t)l * NTYPE * NHEAD * 1024;
    const float* WEl = W_E + (size_t)l * ETYPE * NHEAD * 1024;
    const float* mul = mu + (size_t)l * NHEAD * ETYPE;
    const float* Wol = Wo + (size_t)l * DMODEL * DMODEL;
    const float* bol = bo + (size_t)l * DMODEL;
    const float* w1l = w1 + (size_t)l * DMODEL * 4 * DMODEL;
    const float* b1l = b1 + (size_t)l * 4 * DMODEL;
    const float* w2l = w2 + (size_t)l * 4 * DMODEL * DMODEL;
    const float* b2l = b2 + (size_t)l * DMODEL;

    qkv_kernel<<<N, 256, 0, stream>>>(xbuf, ntype, WQl, WKl, WVl, WEl, Q, V, Kt);
    score_kernel<<<(int)((EH + 255) / 256), 256, 0, stream>>>(
        src, dst, etype, Q, Kt, mul, scores, E);
    agg_kernel<<<N, 256, 0, stream>>>(off, csr, src, scores, V, agg);

    // attn projection + bias
    gemm_kernel<0><<<dim3(DMODEL / 64, gm), 256, 0, stream>>>(
        agg, Wol, bol, fout, N, DMODEL, DMODEL);
    // x = LN(x + attn)
    ln_kernel<<<N, 256, 0, stream>>>(xbuf, fout,
        ln1g + (size_t)l * DMODEL, ln1b + (size_t)l * DMODEL, xbuf);
    // h1 = gelu(x @ w1 + b1)
    gemm_kernel<1><<<dim3(4 * DMODEL / 64, gm), 256, 0, stream>>>(
        xbuf, w1l, b1l, h1, N, DMODEL, 4 * DMODEL);
    // f = h1 @ w2 + b2
    gemm_kernel<0><<<dim3(DMODEL / 64, gm), 256, 0, stream>>>(
        h1, w2l, b2l, fout, N, 4 * DMODEL, DMODEL);
    // x = LN(x + f)
    ln_kernel<<<N, 256, 0, stream>>>(xbuf, fout,
        ln2g + (size_t)l * DMODEL, ln2b + (size_t)l * DMODEL, xbuf);
  }

  // final LN -> d_out
  ln_kernel<<<N, 256, 0, stream>>>(xbuf, nullptr, outg, outb, (float*)d_out);
}

// Round 2
// 1667.385 us; speedup vs baseline: 1.4081x; 1.4081x over previous
//
#include <hip/hip_runtime.h>
#include <math.h>

#define HDIM 32
#define NHEAD 8
#define DMODEL 256
#define NTYPE 4
#define ETYPE 3
#define NLAYER 3

typedef unsigned short u16;
typedef __bf16 bf16x8 __attribute__((ext_vector_type(8)));
typedef float f32x4 __attribute__((ext_vector_type(4)));

__device__ __forceinline__ u16 f2bf(float f) {
  union { float f; unsigned u; } v; v.f = f;
  unsigned r = v.u + 0x7FFF + ((v.u >> 16) & 1);
  return (u16)(r >> 16);
}

#define GLDS16(g, l)                                              \
  __builtin_amdgcn_global_load_lds(                               \
      (const __attribute__((address_space(1))) void*)(g),         \
      (__attribute__((address_space(3))) void*)(l), 16, 0, 0)

// ---------------------------------------------------------------------------
// CSR build (edge structure is layer-invariant; built once per launch)
// ---------------------------------------------------------------------------
__global__ void count_deg_kernel(const int* __restrict__ dst, int* __restrict__ deg, int E) {
  int tid = blockIdx.x * 256 + threadIdx.x;
  if (tid < E) atomicAdd(&deg[dst[tid]], 1);
}

__global__ __launch_bounds__(1024) void scan_kernel(const int* __restrict__ deg,
                                                    int* __restrict__ off, int n) {
  __shared__ int part[1024];
  int t = threadIdx.x;
  int chunk = (n + 1023) >> 10;
  int base = t * chunk;
  int s = 0;
  for (int i = 0; i < chunk; ++i) {
    int idx = base + i;
    if (idx < n) s += deg[idx];
  }
  part[t] = s;
  __syncthreads();
  for (int o = 1; o < 1024; o <<= 1) {
    int v = (t >= o) ? part[t - o] : 0;
    __syncthreads();
    part[t] += v;
    __syncthreads();
  }
  int run = part[t] - s;
  for (int i = 0; i < chunk; ++i) {
    int idx = base + i;
    if (idx < n) { off[idx] = run; run += deg[idx]; }
  }
  if (t == 1023) off[n] = part[1023];
}

__global__ void scatter_kernel(const int* __restrict__ dst, const int* __restrict__ off,
                               int* __restrict__ cursor, int* __restrict__ csr, int E) {
  int tid = blockIdx.x * 256 + threadIdx.x;
  if (tid < E) {
    int d = dst[tid];
    int p = atomicAdd(&cursor[d], 1);
    csr[off[d] + p] = tid;
  }
}

// ---------------------------------------------------------------------------
// fp32 [K,Nc] -> bf16 transposed [Nc,K]; blockIdx.z = layer
// ---------------------------------------------------------------------------
__global__ __launch_bounds__(256) void convT_kernel(const float* __restrict__ W,
                                                    u16* __restrict__ Wt, int K, int Nc) {
  __shared__ float tile[32][33];
  int bk = blockIdx.y * 32, bn = blockIdx.x * 32;
  const float* Wz = W + (size_t)blockIdx.z * K * Nc;
  u16* Wtz = Wt + (size_t)blockIdx.z * K * Nc;
  int tx = threadIdx.x & 31, ty = threadIdx.x >> 5;  // 32 x 8
  for (int r = ty; r < 32; r += 8)
    tile[r][tx] = Wz[(size_t)(bk + r) * Nc + bn + tx];
  __syncthreads();
  for (int r = ty; r < 32; r += 8)
    Wtz[(size_t)(bn + r) * K + bk + tx] = f2bf(tile[tx][r]);
}

// ---------------------------------------------------------------------------
// Typed per-node transforms: Q, V, K-tilde (K pre-transformed by all 3 edge
// types -> avoids per-edge K@W_E matmul: E/N=16 >> TE=3)
// ---------------------------------------------------------------------------
__global__ __launch_bounds__(256) void qkv_kernel(
    const float* __restrict__ x, const int* __restrict__ node_type,
    const float* __restrict__ WQ, const float* __restrict__ WK,
    const float* __restrict__ WV, const float* __restrict__ WE,
    float* __restrict__ Q, float* __restrict__ V, float* __restrict__ Kt) {
  int n = blockIdx.x;
  int t = threadIdx.x;
  int h = t >> 5, e = t & 31;
  __shared__ float xs[256];
  __shared__ float ks[256];
  xs[t] = x[(size_t)n * 256 + t];
  __syncthreads();
  int nt = node_type[n];
  const float* xh = &xs[h * 32];
  const float* wq = WQ + ((size_t)nt * NHEAD + h) * 1024;
  const float* wk = WK + ((size_t)nt * NHEAD + h) * 1024;
  const float* wv = WV + ((size_t)nt * NHEAD + h) * 1024;
  float qa = 0.f, ka = 0.f, va = 0.f;
#pragma unroll
  for (int d = 0; d < 32; ++d) {
    float xv = xh[d];
    qa += xv * wq[d * 32 + e];
    ka += xv * wk[d * 32 + e];
    va += xv * wv[d * 32 + e];
  }
  Q[(size_t)n * 256 + t] = qa;
  V[(size_t)n * 256 + t] = va;
  ks[t] = ka;
  __syncthreads();
  const float* kh = &ks[h * 32];
  for (int et = 0; et < ETYPE; ++et) {
    const float* we = WE + ((size_t)et * NHEAD + h) * 1024;
    float a = 0.f;
#pragma unroll
    for (int d = 0; d < 32; ++d) a += kh[d] * we[d * 32 + e];
    Kt[(size_t)n * (ETYPE * 256) + et * 256 + t] = a;
  }
}

// ---------------------------------------------------------------------------
// Edge scores
// ---------------------------------------------------------------------------
__global__ __launch_bounds__(256) void score_kernel(
    const int* __restrict__ src, const int* __restrict__ dst,
    const int* __restrict__ etype, const float* __restrict__ Q,
    const float* __restrict__ Kt, const float* __restrict__ mu,
    float* __restrict__ scores, int E) {
  int tid = blockIdx.x * 256 + threadIdx.x;
  if (tid >= E * NHEAD) return;
  int eid = tid >> 3, h = tid & 7;
  int s = src[eid], d = dst[eid], t = etype[eid];
  const float4* q = (const float4*)(Q + (size_t)d * 256 + h * 32);
  const float4* k = (const float4*)(Kt + ((size_t)s * ETYPE + t) * 256 + h * 32);
  float acc = 0.f;
#pragma unroll
  for (int i = 0; i < 8; ++i) {
    float4 a = q[i], b = k[i];
    acc += a.x * b.x + a.y * b.y + a.z * b.z + a.w * b.w;
  }
  scores[tid] = acc * 0.17677669529663687f * mu[h * ETYPE + t];
}

// ---------------------------------------------------------------------------
// Segment softmax + weighted V aggregation -> bf16 agg (GEMM A-operand)
// ---------------------------------------------------------------------------
__global__ __launch_bounds__(256) void agg_kernel(
    const int* __restrict__ off, const int* __restrict__ csr,
    const int* __restrict__ src, const float* __restrict__ scores,
    const float* __restrict__ V, u16* __restrict__ aggb) {
  int n = blockIdx.x;
  int t = threadIdx.x;
  int h = t >> 5, j = t & 31;
  int s0 = off[n], s1 = off[n + 1];
  float m = -1e9f;
  for (int k = s0 + j; k < s1; k += 32) {
    int e = csr[k];
    m = fmaxf(m, scores[(size_t)e * 8 + h]);
  }
  for (int o = 16; o > 0; o >>= 1) m = fmaxf(m, __shfl_xor(m, o, 32));
  float ssum = 0.f;
  for (int k = s0 + j; k < s1; k += 32) {
    int e = csr[k];
    ssum += expf(scores[(size_t)e * 8 + h] - m);
  }
  for (int o = 16; o > 0; o >>= 1) ssum += __shfl_xor(ssum, o, 32);
  float inv = 1.f / (ssum + 1e-10f);
  float acc = 0.f;
  for (int k = s0; k < s1; ++k) {
    int e = csr[k];
    float w = expf(scores[(size_t)e * 8 + h] - m) * inv;
    int sn = src[e];
    acc += w * V[(size_t)sn * 256 + h * 32 + j];
  }
  aggb[(size_t)n * 256 + t] = f2bf(acc);
}

// ---------------------------------------------------------------------------
// bf16 MFMA GEMM (m97 structure): C[M,Nc] = A[M,K] @ Bt[Nc,K]^T + bias
// 128x128 tile, 4 waves (2x2), BK=32, 16x16x32 MFMA, global_load_lds w=16.
// EPI 0: fp32 out + bias.  EPI 1: bf16 out + bias + exact GELU.
// ---------------------------------------------------------------------------
template <int EPI>
__global__ __launch_bounds__(256) void gemm_mfma(
    const u16* __restrict__ A, const u16* __restrict__ Bt,
    const float* __restrict__ bias, float* __restrict__ Cf,
    u16* __restrict__ Cb, int M, int K, int Nc) {
  __shared__ u16 As[128 * 32];
  __shared__ u16 Bs[128 * 32];
  const int t = threadIdx.x;
  const int lane = t & 63;
  const int w = t >> 6;
  const int row0 = blockIdx.y * 128;
  const int col0 = blockIdx.x * 128;
  const int wm = (w >> 1) * 64, wn = (w & 1) * 64;

  f32x4 acc[4][4] = {};

  const int sr = lane >> 2;          // 0..15 row within chunk
  const int sk = (lane & 3) * 8;     // k element offset (granule)

  for (int k0 = 0; k0 < K; k0 += 32) {
#pragma unroll
    for (int c = 0; c < 2; ++c) {
      const int chunk = w * 2 + c;       // 0..7
      const int r = chunk * 16 + sr;     // 0..127
      int ra = row0 + r; if (ra >= M) ra = M - 1;     // clamp tail reads
      GLDS16(A + (size_t)ra * K + k0 + sk, &As[(chunk * 64 + lane) * 8]);
      GLDS16(Bt + (size_t)(col0 + r) * K + k0 + sk, &Bs[(chunk * 64 + lane) * 8]);
    }
    __syncthreads();
    bf16x8 af[4], bfr[4];
    const int ko = (lane >> 4) * 8;
    const int lr = lane & 15;
#pragma unroll
    for (int i = 0; i < 4; ++i)
      af[i] = *(const bf16x8*)&As[(wm + i * 16 + lr) * 32 + ko];
#pragma unroll
    for (int j = 0; j < 4; ++j)
      bfr[j] = *(const bf16x8*)&Bs[(wn + j * 16 + lr) * 32 + ko];
#pragma unroll
    for (int i = 0; i < 4; ++i)
#pragma unroll
      for (int j = 0; j < 4; ++j)
        acc[i][j] = __builtin_amdgcn_mfma_f32_16x16x32_bf16(af[i], bfr[j], acc[i][j], 0, 0, 0);
    __syncthreads();
  }

  // epilogue: C/D layout col=lane&15, row=(lane>>4)*4+reg
  const int lc = lane & 15;
  const int lrow = (lane >> 4) * 4;
#pragma unroll
  for (int i = 0; i < 4; ++i) {
#pragma unroll
    for (int r = 0; r < 4; ++r) {
      int gr = row0 + wm + i * 16 + lrow + r;
      if (gr >= M) continue;
#pragma unroll
      for (int j = 0; j < 4; ++j) {
        int gc = col0 + wn + j * 16 + lc;
        float v = acc[i][j][r] + bias[gc];
        if (EPI == 1) {
          v = 0.5f * v * (1.f + erff(v * 0.70710678118654752f));
          Cb[(size_t)gr * Nc + gc] = f2bf(v);
        } else {
          Cf[(size_t)gr * Nc + gc] = v;
        }
      }
    }
  }
}

// ---------------------------------------------------------------------------
// LayerNorm rows of 256: out = LN(xin + res) * g + b; optional bf16 copy
// ---------------------------------------------------------------------------
__global__ __launch_bounds__(256) void ln_kernel(
    const float* __restrict__ xin, const float* __restrict__ res,
    const float* __restrict__ g, const float* __restrict__ b,
    float* __restrict__ out, u16* __restrict__ outb) {
  int n = blockIdx.x;
  int t = threadIdx.x;
  __shared__ float red[8];
  size_t idx = (size_t)n * 256 + t;
  float r = xin[idx] + (res ? res[idx] : 0.f);
  float s = r;
  for (int o = 32; o > 0; o >>= 1) s += __shfl_xor(s, o, 64);
  if ((t & 63) == 0) red[t >> 6] = s;
  __syncthreads();
  float m = (red[0] + red[1] + red[2] + red[3]) * (1.f / 256.f);
  float d = r - m;
  float s2 = d * d;
  for (int o = 32; o > 0; o >>= 1) s2 += __shfl_xor(s2, o, 64);
  if ((t & 63) == 0) red[4 + (t >> 6)] = s2;
  __syncthreads();
  float var = (red[4] + red[5] + red[6] + red[7]) * (1.f / 256.f);
  float o = d * rsqrtf(var + 1e-5f) * g[t] + b[t];
  out[idx] = o;
  if (outb) outb[idx] = f2bf(o);
}

// ---------------------------------------------------------------------------
extern "C" void kernel_launch(void* const* d_in, const int* in_sizes, int n_in,
                              void* d_out, int out_size, void* d_ws, size_t ws_size,
                              hipStream_t stream) {
  const float* x_in   = (const float*)d_in[0];
  const int*   ei     = (const int*)d_in[1];
  const int*   etype  = (const int*)d_in[2];
  const int*   ntype  = (const int*)d_in[3];
  const float* W_Q    = (const float*)d_in[4];
  const float* W_K    = (const float*)d_in[5];
  const float* W_V    = (const float*)d_in[6];
  const float* W_E    = (const float*)d_in[7];
  const float* mu     = (const float*)d_in[8];
  const float* Wo     = (const float*)d_in[9];
  const float* bo     = (const float*)d_in[10];
  const float* ln1g   = (const float*)d_in[11];
  const float* ln1b   = (const float*)d_in[12];
  const float* ln2g   = (const float*)d_in[13];
  const float* ln2b   = (const float*)d_in[14];
  const float* w1     = (const float*)d_in[15];
  const float* b1     = (const float*)d_in[16];
  const float* w2     = (const float*)d_in[17];
  const float* b2     = (const float*)d_in[18];
  const float* outg   = (const float*)d_in[19];
  const float* outb   = (const float*)d_in[20];

  const int N = in_sizes[0] / DMODEL;    // 20000
  const int E = in_sizes[1] / 2;         // 320000
  const int* src = ei;
  const int* dst = ei + E;

  const size_t NF = (size_t)N * DMODEL;
  const size_t EH = (size_t)E * NHEAD;

  // ---- workspace layout ----
  float* f      = (float*)d_ws;
  float* xbuf   = f;                 // NF fp32
  float* Q      = f + NF;            // NF   (dead after score)
  float* V      = f + 2 * NF;        // NF   (dead after agg)
  float* Kt     = f + 3 * NF;        // 3NF  (dead after score)
  float* scores = f + 6 * NF;        // EH
  float* fout   = Kt;                // NF, aliases Kt[0:NF] (dead by GEMM time)
  u16*   h1b    = (u16*)Q;           // N*1024 bf16 = 2NF*4 bytes, aliases Q+V
  u16*   xb     = (u16*)(f + 6 * NF + EH);       // NF bf16
  u16*   aggb   = xb + NF;                       // NF bf16
  u16*   wt     = aggb + NF;                     // transposed bf16 weights
  u16*   Wot    = wt;                            // 3 * 256*256
  u16*   w1t    = Wot + 3 * 65536;               // 3 * 1024*256  ([n][k])
  u16*   w2t    = w1t + 3 * 262144;              // 3 * 256*1024  ([n][k])
  int*   ip     = (int*)(w2t + 3 * 262144);
  int*   off    = ip;                // N+1
  int*   csr    = ip + (N + 1);      // E
  int*   cursor = csr + E;           // N (doubles as deg)

  // ---- CSR build (once) ----
  hipMemsetAsync(cursor, 0, (size_t)N * sizeof(int), stream);
  count_deg_kernel<<<(E + 255) / 256, 256, 0, stream>>>(dst, cursor, E);
  scan_kernel<<<1, 1024, 0, stream>>>(cursor, off, N);
  hipMemsetAsync(cursor, 0, (size_t)N * sizeof(int), stream);
  scatter_kernel<<<(E + 255) / 256, 256, 0, stream>>>(dst, off, cursor, csr, E);

  // ---- weight convert + transpose to bf16 [N,K] (all layers, once) ----
  convT_kernel<<<dim3(DMODEL / 32, DMODEL / 32, NLAYER), 256, 0, stream>>>(
      Wo, Wot, DMODEL, DMODEL);
  convT_kernel<<<dim3(4 * DMODEL / 32, DMODEL / 32, NLAYER), 256, 0, stream>>>(
      w1, w1t, DMODEL, 4 * DMODEL);
  convT_kernel<<<dim3(DMODEL / 32, 4 * DMODEL / 32, NLAYER), 256, 0, stream>>>(
      w2, w2t, 4 * DMODEL, DMODEL);

  // ---- x working copy ----
  hipMemcpyAsync(xbuf, x_in, NF * sizeof(float), hipMemcpyDeviceToDevice, stream);

  const int gm = (N + 127) / 128;
  for (int l = 0; l < NLAYER; ++l) {
    const float* WQl = W_Q + (size_t)l * NTYPE * NHEAD * 1024;
    const float* WKl = W_K + (size_t)l * NTYPE * NHEAD * 1024;
    const float* WVl = W_V + (size_t)l * NTYPE * NHEAD * 1024;
    const float* WEl = W_E + (size_t)l * ETYPE * NHEAD * 1024;
    const float* mul = mu + (size_t)l * NHEAD * ETYPE;

    qkv_kernel<<<N, 256, 0, stream>>>(xbuf, ntype, WQl, WKl, WVl, WEl, Q, V, Kt);
    score_kernel<<<(int)((EH + 255) / 256), 256, 0, stream>>>(
        src, dst, etype, Q, Kt, mul, scores, E);
    agg_kernel<<<N, 256, 0, stream>>>(off, csr, src, scores, V, aggb);

    // attn projection: fout = aggb @ Wo^T(t) + bo
    gemm_mfma<0><<<dim3(DMODEL / 128, gm), 256, 0, stream>>>(
        aggb, Wot + (size_t)l * 65536, bo + (size_t)l * DMODEL,
        fout, nullptr, N, DMODEL, DMODEL);
    // x = LN(x + attn), also bf16 copy for FFN
    ln_kernel<<<N, 256, 0, stream>>>(xbuf, fout,
        ln1g + (size_t)l * DMODEL, ln1b + (size_t)l * DMODEL, xbuf, xb);
    // h1 = gelu(x @ w1 + b1) -> bf16
    gemm_mfma<1><<<dim3(4 * DMODEL / 128, gm), 256, 0, stream>>>(
        xb, w1t + (size_t)l * 262144, b1 + (size_t)l * 4 * DMODEL,
        nullptr, h1b, N, DMODEL, 4 * DMODEL);
    // fout = h1 @ w2 + b2
    gemm_mfma<0><<<dim3(DMODEL / 128, gm), 256, 0, stream>>>(
        h1b, w2t + (size_t)l * 262144, b2 + (size_t)l * DMODEL,
        fout, nullptr, N, 4 * DMODEL, DMODEL);
    // x = LN(x + f)
    ln_kernel<<<N, 256, 0, stream>>>(xbuf, fout,
        ln2g + (size_t)l * DMODEL, ln2b + (size_t)l * DMODEL, xbuf, nullptr);
  }

  ln_kernel<<<N, 256, 0, stream>>>(xbuf, nullptr, outg, outb, (float*)d_out, nullptr);
}

// Round 3
// 1372.499 us; speedup vs baseline: 1.7107x; 1.2149x over previous
//
#include <hip/hip_runtime.h>
#include <math.h>

#define HDIM 32
#define NHEAD 8
#define DMODEL 256
#define NTYPE 4
#define ETYPE 3
#define NLAYER 3

typedef unsigned short u16;
typedef __bf16 bf16x8 __attribute__((ext_vector_type(8)));
typedef float f32x4 __attribute__((ext_vector_type(4)));

__device__ __forceinline__ u16 f2bf(float f) {
  union { float f; unsigned u; } v; v.f = f;
  unsigned r = v.u + 0x7FFF + ((v.u >> 16) & 1);
  return (u16)(r >> 16);
}

#define GLDS16(g, l)                                              \
  __builtin_amdgcn_global_load_lds(                               \
      (const __attribute__((address_space(1))) void*)(g),         \
      (__attribute__((address_space(3))) void*)(l), 16, 0, 0)

// ---------------------------------------------------------------------------
// CSR build (dst-sorted edges; layer-invariant, built once per launch)
// ---------------------------------------------------------------------------
__global__ void count_deg_kernel(const int* __restrict__ dst, int* __restrict__ deg, int E) {
  int tid = blockIdx.x * 256 + threadIdx.x;
  if (tid < E) atomicAdd(&deg[dst[tid]], 1);
}

__global__ __launch_bounds__(1024) void scan_kernel(const int* __restrict__ deg,
                                                    int* __restrict__ off, int n) {
  __shared__ int part[1024];
  int t = threadIdx.x;
  int chunk = (n + 1023) >> 10;
  int base = t * chunk;
  int s = 0;
  for (int i = 0; i < chunk; ++i) {
    int idx = base + i;
    if (idx < n) s += deg[idx];
  }
  part[t] = s;
  __syncthreads();
  for (int o = 1; o < 1024; o <<= 1) {
    int v = (t >= o) ? part[t - o] : 0;
    __syncthreads();
    part[t] += v;
    __syncthreads();
  }
  int run = part[t] - s;
  for (int i = 0; i < chunk; ++i) {
    int idx = base + i;
    if (idx < n) { off[idx] = run; run += deg[idx]; }
  }
  if (t == 1023) off[n] = part[1023];
}

__global__ void scatter_kernel(const int* __restrict__ dst, const int* __restrict__ off,
                               int* __restrict__ cursor, int* __restrict__ csr, int E) {
  int tid = blockIdx.x * 256 + threadIdx.x;
  if (tid < E) {
    int d = dst[tid];
    int p = atomicAdd(&cursor[d], 1);
    csr[off[d] + p] = tid;
  }
}

// ---------------------------------------------------------------------------
// Node-type buckets (layer-invariant)
// ---------------------------------------------------------------------------
__global__ void tcount_kernel(const int* __restrict__ nt, int* __restrict__ tcnt, int N) {
  int tid = blockIdx.x * 256 + threadIdx.x;
  if (tid < N) atomicAdd(&tcnt[nt[tid]], 1);
}

__global__ void tscan_kernel(const int* __restrict__ tcnt, int* __restrict__ toff,
                             int* __restrict__ tile_off) {
  if (threadIdx.x == 0 && blockIdx.x == 0) {
    int o = 0, to = 0;
    for (int t = 0; t < NTYPE; ++t) {
      toff[t] = o; tile_off[t] = to;
      o += tcnt[t]; to += (tcnt[t] + 63) >> 6;
    }
    toff[NTYPE] = o; tile_off[NTYPE] = to;
  }
}

__global__ void tscatter_kernel(const int* __restrict__ nt, const int* __restrict__ toff,
                                int* __restrict__ tcur, int* __restrict__ tidx, int N) {
  int tid = blockIdx.x * 256 + threadIdx.x;
  if (tid < N) {
    int ty = nt[tid];
    int p = atomicAdd(&tcur[ty], 1);
    tidx[toff[ty] + p] = tid;
  }
}

// ---------------------------------------------------------------------------
// x fp32 -> bf16 mirror
// ---------------------------------------------------------------------------
__global__ void xconv_kernel(const float* __restrict__ x, u16* __restrict__ xb, int n4) {
  int i = blockIdx.x * 256 + threadIdx.x;
  if (i < n4) {
    float4 v = ((const float4*)x)[i];
    ushort4 o = { f2bf(v.x), f2bf(v.y), f2bf(v.z), f2bf(v.w) };
    ((ushort4*)xb)[i] = o;
  }
}

// ---------------------------------------------------------------------------
// Weight prep: per (l,type,head) build bf16 B-operand-layout [col][k] mats:
// mat0 = WQ^T, mat1 = WV^T, mat2..4 = (WK @ WE[et])^T   (K-fusion: no per-edge
// or per-node K intermediate at all)
// ---------------------------------------------------------------------------
__global__ __launch_bounds__(256) void wprep_kernel(
    const float* __restrict__ W_Q, const float* __restrict__ W_K,
    const float* __restrict__ W_V, const float* __restrict__ W_E,
    u16* __restrict__ wqkvb) {
  int b = blockIdx.x;                    // ((l*NTYPE+t)*NHEAD+h)
  int h = b & 7, tt = (b >> 3) & 3, l = b >> 5;
  __shared__ float wk[1024];
  __shared__ float we[3][1024];
  int t = threadIdx.x;
  const float* WKp = W_K + (((size_t)l * NTYPE + tt) * NHEAD + h) * 1024;
  for (int i = t; i < 1024; i += 256) wk[i] = WKp[i];
  for (int et = 0; et < ETYPE; ++et) {
    const float* WEp = W_E + (((size_t)l * ETYPE + et) * NHEAD + h) * 1024;
    for (int i = t; i < 1024; i += 256) we[et][i] = WEp[i];
  }
  __syncthreads();
  const float* WQp = W_Q + (((size_t)l * NTYPE + tt) * NHEAD + h) * 1024;
  const float* WVp = W_V + (((size_t)l * NTYPE + tt) * NHEAD + h) * 1024;
  u16* out = wqkvb + (size_t)b * 5120;
  for (int i = t; i < 1024; i += 256) {
    int col = i >> 5, k = i & 31;
    out[i] = f2bf(WQp[k * 32 + col]);
    out[1024 + i] = f2bf(WVp[k * 32 + col]);
#pragma unroll
    for (int et = 0; et < ETYPE; ++et) {
      float a = 0.f;
#pragma unroll
      for (int d = 0; d < 32; ++d) a += wk[k * 32 + d] * we[et][d * 32 + col];
      out[(2 + et) * 1024 + i] = f2bf(a);
    }
  }
}

// ---------------------------------------------------------------------------
// QKV via MFMA over type buckets. Block = (64-node tile of one type) x head.
// 5 outputs per node-head: Q, V, Kt[3]. One 16x16x32 MFMA per 16-row x 16-col.
// ---------------------------------------------------------------------------
__global__ __launch_bounds__(256) void qkv_mfma(
    const u16* __restrict__ xb, const int* __restrict__ tidx,
    const int* __restrict__ toff, const int* __restrict__ tile_off,
    const u16* __restrict__ wqkvb_l,
    u16* __restrict__ Qb, u16* __restrict__ Vb, u16* __restrict__ Ktb) {
  __shared__ u16 smem[10240];  // phase1: x[64][32] @0, w[5][1024] @2048; phase2: out[5][64][32]
  int bx = blockIdx.x, h = blockIdx.y;
  if (bx >= tile_off[NTYPE]) return;
  int ty = 0;
  while (bx >= tile_off[ty + 1]) ++ty;
  int lt = bx - tile_off[ty];
  int base = toff[ty] + lt * 64;
  int cnt = min(64, toff[ty + 1] - toff[ty] - lt * 64);
  int t = threadIdx.x;
  {
    int row = t >> 2, q = t & 3;
    int node = tidx[base + min(row, cnt - 1)];
    *(uint4*)&smem[row * 32 + q * 8] =
        *(const uint4*)&xb[(size_t)node * 256 + h * 32 + q * 8];
  }
  const u16* wsrc = wqkvb_l + ((size_t)ty * NHEAD + h) * 5120;
  for (int c = t; c < 640; c += 256)
    *(uint4*)&smem[2048 + c * 8] = *(const uint4*)&wsrc[c * 8];
  __syncthreads();

  int lane = t & 63, w = t >> 6;
  int m = lane & 15, q = lane >> 4;
  bf16x8 af = *(const bf16x8*)&smem[(w * 16 + m) * 32 + q * 8];
  f32x4 acc[5][2];
#pragma unroll
  for (int mt = 0; mt < 5; ++mt)
#pragma unroll
    for (int c = 0; c < 2; ++c) {
      bf16x8 bf = *(const bf16x8*)&smem[2048 + mt * 1024 + (c * 16 + m) * 32 + q * 8];
      acc[mt][c] = __builtin_amdgcn_mfma_f32_16x16x32_bf16(af, bf, (f32x4){0.f, 0.f, 0.f, 0.f}, 0, 0, 0);
    }
  __syncthreads();
  // C/D layout: col = lane&15, row = (lane>>4)*4 + r
#pragma unroll
  for (int mt = 0; mt < 5; ++mt)
#pragma unroll
    for (int c = 0; c < 2; ++c)
#pragma unroll
      for (int r = 0; r < 4; ++r)
        smem[mt * 2048 + (w * 16 + q * 4 + r) * 32 + c * 16 + m] = f2bf(acc[mt][c][r]);
  __syncthreads();
  {
    int row = t >> 2, q4 = t & 3;
    if (row < cnt) {
      int node = tidx[base + row];
      *(uint4*)&Qb[(size_t)node * 256 + h * 32 + q4 * 8] =
          *(const uint4*)&smem[row * 32 + q4 * 8];
      *(uint4*)&Vb[(size_t)node * 256 + h * 32 + q4 * 8] =
          *(const uint4*)&smem[2048 + row * 32 + q4 * 8];
#pragma unroll
      for (int et = 0; et < ETYPE; ++et)
        *(uint4*)&Ktb[((size_t)node * ETYPE + et) * 256 + h * 32 + q4 * 8] =
            *(const uint4*)&smem[(2 + et) * 2048 + row * 32 + q4 * 8];
    }
  }
}

// ---------------------------------------------------------------------------
// Edge scores (bf16 operands, fp32 accumulate)
// ---------------------------------------------------------------------------
__global__ __launch_bounds__(256) void score_kernel(
    const int* __restrict__ src, const int* __restrict__ dst,
    const int* __restrict__ etype, const u16* __restrict__ Qb,
    const u16* __restrict__ Ktb, const float* __restrict__ mu,
    float* __restrict__ scores, int E) {
  int tid = blockIdx.x * 256 + threadIdx.x;
  if (tid >= E * NHEAD) return;
  int eid = tid >> 3, h = tid & 7;
  int s = src[eid], d = dst[eid], t = etype[eid];
  const bf16x8* q = (const bf16x8*)(Qb + (size_t)d * 256 + h * 32);
  const bf16x8* k = (const bf16x8*)(Ktb + ((size_t)s * ETYPE + t) * 256 + h * 32);
  float acc = 0.f;
#pragma unroll
  for (int i = 0; i < 4; ++i) {
    bf16x8 a = q[i], b = k[i];
#pragma unroll
    for (int j = 0; j < 8; ++j) acc += (float)a[j] * (float)b[j];
  }
  scores[tid] = acc * 0.17677669529663687f * mu[h * ETYPE + t];
}

// ---------------------------------------------------------------------------
// Segment softmax + weighted V aggregation -> bf16 agg
// ---------------------------------------------------------------------------
__global__ __launch_bounds__(256) void agg_kernel(
    const int* __restrict__ off, const int* __restrict__ csr,
    const int* __restrict__ src, const float* __restrict__ scores,
    const u16* __restrict__ Vb, u16* __restrict__ aggb) {
  int n = blockIdx.x;
  int t = threadIdx.x;
  int h = t >> 5, j = t & 31;
  int s0 = off[n], s1 = off[n + 1];
  float m = -1e9f;
  for (int k = s0 + j; k < s1; k += 32) {
    int e = csr[k];
    m = fmaxf(m, scores[(size_t)e * 8 + h]);
  }
  for (int o = 16; o > 0; o >>= 1) m = fmaxf(m, __shfl_xor(m, o, 32));
  float ssum = 0.f;
  for (int k = s0 + j; k < s1; k += 32) {
    int e = csr[k];
    ssum += expf(scores[(size_t)e * 8 + h] - m);
  }
  for (int o = 16; o > 0; o >>= 1) ssum += __shfl_xor(ssum, o, 32);
  float inv = 1.f / (ssum + 1e-10f);
  float acc = 0.f;
  for (int k = s0; k < s1; ++k) {
    int e = csr[k];
    float w = expf(scores[(size_t)e * 8 + h] - m) * inv;
    int sn = src[e];
    acc += w * (float)*(const __bf16*)&Vb[(size_t)sn * 256 + h * 32 + j];
  }
  aggb[(size_t)n * 256 + t] = f2bf(acc);
}

// ---------------------------------------------------------------------------
// fp32 [K,Nc] -> bf16 transposed [Nc,K]
// ---------------------------------------------------------------------------
__global__ __launch_bounds__(256) void convT_kernel(const float* __restrict__ W,
                                                    u16* __restrict__ Wt, int K, int Nc) {
  __shared__ float tile[32][33];
  int bk = blockIdx.y * 32, bn = blockIdx.x * 32;
  const float* Wz = W + (size_t)blockIdx.z * K * Nc;
  u16* Wtz = Wt + (size_t)blockIdx.z * K * Nc;
  int tx = threadIdx.x & 31, ty = threadIdx.x >> 5;
  for (int r = ty; r < 32; r += 8)
    tile[r][tx] = Wz[(size_t)(bk + r) * Nc + bn + tx];
  __syncthreads();
  for (int r = ty; r < 32; r += 8)
    Wtz[(size_t)(bn + r) * K + bk + tx] = f2bf(tile[tx][r]);
}

// ---------------------------------------------------------------------------
// bf16 MFMA GEMM (m97 structure): C[M,Nc] = A[M,K] @ Bt[Nc,K]^T + bias
// ---------------------------------------------------------------------------
template <int EPI>  // 0: fp32 out + bias; 1: bf16 out + bias + exact GELU
__global__ __launch_bounds__(256) void gemm_mfma(
    const u16* __restrict__ A, const u16* __restrict__ Bt,
    const float* __restrict__ bias, float* __restrict__ Cf,
    u16* __restrict__ Cb, int M, int K, int Nc) {
  __shared__ u16 As[128 * 32];
  __shared__ u16 Bs[128 * 32];
  const int t = threadIdx.x;
  const int lane = t & 63;
  const int w = t >> 6;
  const int row0 = blockIdx.y * 128;
  const int col0 = blockIdx.x * 128;
  const int wm = (w >> 1) * 64, wn = (w & 1) * 64;

  f32x4 acc[4][4] = {};
  const int sr = lane >> 2;
  const int sk = (lane & 3) * 8;

  for (int k0 = 0; k0 < K; k0 += 32) {
#pragma unroll
    for (int c = 0; c < 2; ++c) {
      const int chunk = w * 2 + c;
      const int r = chunk * 16 + sr;
      int ra = row0 + r; if (ra >= M) ra = M - 1;
      GLDS16(A + (size_t)ra * K + k0 + sk, &As[(chunk * 64 + lane) * 8]);
      GLDS16(Bt + (size_t)(col0 + r) * K + k0 + sk, &Bs[(chunk * 64 + lane) * 8]);
    }
    __syncthreads();
    bf16x8 af[4], bfr[4];
    const int ko = (lane >> 4) * 8;
    const int lr = lane & 15;
#pragma unroll
    for (int i = 0; i < 4; ++i)
      af[i] = *(const bf16x8*)&As[(wm + i * 16 + lr) * 32 + ko];
#pragma unroll
    for (int j = 0; j < 4; ++j)
      bfr[j] = *(const bf16x8*)&Bs[(wn + j * 16 + lr) * 32 + ko];
#pragma unroll
    for (int i = 0; i < 4; ++i)
#pragma unroll
      for (int j = 0; j < 4; ++j)
        acc[i][j] = __builtin_amdgcn_mfma_f32_16x16x32_bf16(af[i], bfr[j], acc[i][j], 0, 0, 0);
    __syncthreads();
  }

  const int lc = lane & 15;
  const int lrow = (lane >> 4) * 4;
#pragma unroll
  for (int i = 0; i < 4; ++i) {
#pragma unroll
    for (int r = 0; r < 4; ++r) {
      int gr = row0 + wm + i * 16 + lrow + r;
      if (gr >= M) continue;
#pragma unroll
      for (int j = 0; j < 4; ++j) {
        int gc = col0 + wn + j * 16 + lc;
        float v = acc[i][j][r] + bias[gc];
        if (EPI == 1) {
          v = 0.5f * v * (1.f + erff(v * 0.70710678118654752f));
          Cb[(size_t)gr * Nc + gc] = f2bf(v);
        } else {
          Cf[(size_t)gr * Nc + gc] = v;
        }
      }
    }
  }
}

// ---------------------------------------------------------------------------
// LayerNorm rows of 256: out = LN(xin + res) * g + b; optional bf16 mirror
// ---------------------------------------------------------------------------
__global__ __launch_bounds__(256) void ln_kernel(
    const float* __restrict__ xin, const float* __restrict__ res,
    const float* __restrict__ g, const float* __restrict__ b,
    float* __restrict__ out, u16* __restrict__ outb) {
  int n = blockIdx.x;
  int t = threadIdx.x;
  __shared__ float red[8];
  size_t idx = (size_t)n * 256 + t;
  float r = xin[idx] + (res ? res[idx] : 0.f);
  float s = r;
  for (int o = 32; o > 0; o >>= 1) s += __shfl_xor(s, o, 64);
  if ((t & 63) == 0) red[t >> 6] = s;
  __syncthreads();
  float m = (red[0] + red[1] + red[2] + red[3]) * (1.f / 256.f);
  float d = r - m;
  float s2 = d * d;
  for (int o = 32; o > 0; o >>= 1) s2 += __shfl_xor(s2, o, 64);
  if ((t & 63) == 0) red[4 + (t >> 6)] = s2;
  __syncthreads();
  float var = (red[4] + red[5] + red[6] + red[7]) * (1.f / 256.f);
  float o = d * rsqrtf(var + 1e-5f) * g[t] + b[t];
  out[idx] = o;
  if (outb) outb[idx] = f2bf(o);
}

// ---------------------------------------------------------------------------
extern "C" void kernel_launch(void* const* d_in, const int* in_sizes, int n_in,
                              void* d_out, int out_size, void* d_ws, size_t ws_size,
                              hipStream_t stream) {
  const float* x_in   = (const float*)d_in[0];
  const int*   ei     = (const int*)d_in[1];
  const int*   etype  = (const int*)d_in[2];
  const int*   ntype  = (const int*)d_in[3];
  const float* W_Q    = (const float*)d_in[4];
  const float* W_K    = (const float*)d_in[5];
  const float* W_V    = (const float*)d_in[6];
  const float* W_E    = (const float*)d_in[7];
  const float* mu     = (const float*)d_in[8];
  const float* Wo     = (const float*)d_in[9];
  const float* bo     = (const float*)d_in[10];
  const float* ln1g   = (const float*)d_in[11];
  const float* ln1b   = (const float*)d_in[12];
  const float* ln2g   = (const float*)d_in[13];
  const float* ln2b   = (const float*)d_in[14];
  const float* w1     = (const float*)d_in[15];
  const float* b1     = (const float*)d_in[16];
  const float* w2     = (const float*)d_in[17];
  const float* b2     = (const float*)d_in[18];
  const float* outg   = (const float*)d_in[19];
  const float* outb   = (const float*)d_in[20];

  const int N = in_sizes[0] / DMODEL;    // 20000
  const int E = in_sizes[1] / 2;         // 320000
  const int* src = ei;
  const int* dst = ei + E;

  const size_t NF = (size_t)N * DMODEL;
  const size_t EH = (size_t)E * NHEAD;

  // ---- workspace layout ----
  float* f      = (float*)d_ws;
  float* xbuf   = f;                     // NF fp32 (LN residual master)
  float* fout   = f + NF;                // NF fp32 (GEMM fp32 outputs)
  float* scores = f + 2 * NF;            // EH fp32
  u16*   xb     = (u16*)(f + 2 * NF + EH);  // NF bf16 mirror of x
  u16*   Qb     = xb + NF;               // NF
  u16*   Vb     = Qb + NF;               // NF   } h1b aliases Vb..Ktb
  u16*   Ktb    = Vb + NF;               // 3NF  } (4NF total = N x 1024)
  u16*   h1b    = Vb;                    // alias
  u16*   aggb   = Ktb + 3 * NF;          // NF
  u16*   wqkvb  = aggb + NF;             // 96 * 5120
  u16*   Wot    = wqkvb + (size_t)NLAYER * NTYPE * NHEAD * 5120;
  u16*   w1t    = Wot + 3 * 65536;
  u16*   w2t    = w1t + 3 * 262144;
  int*   ip     = (int*)(w2t + 3 * 262144);
  int*   off    = ip;                    // N+1
  int*   csr    = off + (N + 1);         // E
  int*   cursor = csr + E;               // N (deg, then cursor)
  int*   tidx   = cursor + N;            // N
  int*   toff   = tidx + N;              // NTYPE+1
  int*   tile_off = toff + (NTYPE + 1);  // NTYPE+1
  int*   tcnt   = tile_off + (NTYPE + 1);// NTYPE (also tcur)
  int*   tcur   = tcnt + NTYPE;          // NTYPE

  // ---- CSR + type buckets (once) ----
  hipMemsetAsync(cursor, 0, (size_t)N * sizeof(int), stream);
  hipMemsetAsync(tcnt, 0, 2 * NTYPE * sizeof(int), stream);
  count_deg_kernel<<<(E + 255) / 256, 256, 0, stream>>>(dst, cursor, E);
  scan_kernel<<<1, 1024, 0, stream>>>(cursor, off, N);
  hipMemsetAsync(cursor, 0, (size_t)N * sizeof(int), stream);
  scatter_kernel<<<(E + 255) / 256, 256, 0, stream>>>(dst, off, cursor, csr, E);
  tcount_kernel<<<(N + 255) / 256, 256, 0, stream>>>(ntype, tcnt, N);
  tscan_kernel<<<1, 64, 0, stream>>>(tcnt, toff, tile_off);
  tscatter_kernel<<<(N + 255) / 256, 256, 0, stream>>>(ntype, toff, tcur, tidx, N);

  // ---- weight prep (once) ----
  wprep_kernel<<<NLAYER * NTYPE * NHEAD, 256, 0, stream>>>(W_Q, W_K, W_V, W_E, wqkvb);
  convT_kernel<<<dim3(DMODEL / 32, DMODEL / 32, NLAYER), 256, 0, stream>>>(
      Wo, Wot, DMODEL, DMODEL);
  convT_kernel<<<dim3(4 * DMODEL / 32, DMODEL / 32, NLAYER), 256, 0, stream>>>(
      w1, w1t, DMODEL, 4 * DMODEL);
  convT_kernel<<<dim3(DMODEL / 32, 4 * DMODEL / 32, NLAYER), 256, 0, stream>>>(
      w2, w2t, 4 * DMODEL, DMODEL);

  // ---- x working copies ----
  hipMemcpyAsync(xbuf, x_in, NF * sizeof(float), hipMemcpyDeviceToDevice, stream);
  xconv_kernel<<<(int)((NF / 4 + 255) / 256), 256, 0, stream>>>(x_in, xb, (int)(NF / 4));

  const int gm = (N + 127) / 128;
  const int qtiles = (N + 63) / 64 + NTYPE;  // upper bound on sum of per-type tiles
  for (int l = 0; l < NLAYER; ++l) {
    qkv_mfma<<<dim3(qtiles, NHEAD), 256, 0, stream>>>(
        xb, tidx, toff, tile_off,
        wqkvb + (size_t)l * NTYPE * NHEAD * 5120, Qb, Vb, Ktb);
    score_kernel<<<(int)((EH + 255) / 256), 256, 0, stream>>>(
        src, dst, etype, Qb, Ktb, mu + (size_t)l * NHEAD * ETYPE, scores, E);
    agg_kernel<<<N, 256, 0, stream>>>(off, csr, src, scores, Vb, aggb);

    gemm_mfma<0><<<dim3(DMODEL / 128, gm), 256, 0, stream>>>(
        aggb, Wot + (size_t)l * 65536, bo + (size_t)l * DMODEL,
        fout, nullptr, N, DMODEL, DMODEL);
    ln_kernel<<<N, 256, 0, stream>>>(xbuf, fout,
        ln1g + (size_t)l * DMODEL, ln1b + (size_t)l * DMODEL, xbuf, xb);
    gemm_mfma<1><<<dim3(4 * DMODEL / 128, gm), 256, 0, stream>>>(
        xb, w1t + (size_t)l * 262144, b1 + (size_t)l * 4 * DMODEL,
        nullptr, h1b, N, DMODEL, 4 * DMODEL);
    gemm_mfma<0><<<dim3(DMODEL / 128, gm), 256, 0, stream>>>(
        h1b, w2t + (size_t)l * 262144, b2 + (size_t)l * DMODEL,
        fout, nullptr, N, 4 * DMODEL, DMODEL);
    ln_kernel<<<N, 256, 0, stream>>>(xbuf, fout,
        ln2g + (size_t)l * DMODEL, ln2b + (size_t)l * DMODEL, xbuf, xb);
  }

  ln_kernel<<<N, 256, 0, stream>>>(xbuf, nullptr, outg, outb, (float*)d_out, nullptr);
}

// Round 4
// 1165.803 us; speedup vs baseline: 2.0140x; 1.1773x over previous
//
#include <hip/hip_runtime.h>
#include <math.h>

#define HDIM 32
#define NHEAD 8
#define DMODEL 256
#define NTYPE 4
#define ETYPE 3
#define NLAYER 3

typedef unsigned short u16;
typedef __bf16 bf16x8 __attribute__((ext_vector_type(8)));
typedef float f32x4 __attribute__((ext_vector_type(4)));

__device__ __forceinline__ u16 f2bf(float f) {
  union { float f; unsigned u; } v; v.f = f;
  unsigned r = v.u + 0x7FFF + ((v.u >> 16) & 1);
  return (u16)(r >> 16);
}

#define GLDS16(g, l)                                              \
  __builtin_amdgcn_global_load_lds(                               \
      (const __attribute__((address_space(1))) void*)(g),         \
      (__attribute__((address_space(3))) void*)(l), 16, 0, 0)

// ---------------------------------------------------------------------------
// CSR build (dst-sorted edges; layer-invariant, built once per launch)
// ---------------------------------------------------------------------------
__global__ void count_deg_kernel(const int* __restrict__ dst, int* __restrict__ deg, int E) {
  int tid = blockIdx.x * 256 + threadIdx.x;
  if (tid < E) atomicAdd(&deg[dst[tid]], 1);
}

__global__ __launch_bounds__(1024) void scan_kernel(const int* __restrict__ deg,
                                                    int* __restrict__ off, int n) {
  __shared__ int part[1024];
  int t = threadIdx.x;
  int chunk = (n + 1023) >> 10;
  int base = t * chunk;
  int s = 0;
  for (int i = 0; i < chunk; ++i) {
    int idx = base + i;
    if (idx < n) s += deg[idx];
  }
  part[t] = s;
  __syncthreads();
  for (int o = 1; o < 1024; o <<= 1) {
    int v = (t >= o) ? part[t - o] : 0;
    __syncthreads();
    part[t] += v;
    __syncthreads();
  }
  int run = part[t] - s;
  for (int i = 0; i < chunk; ++i) {
    int idx = base + i;
    if (idx < n) { off[idx] = run; run += deg[idx]; }
  }
  if (t == 1023) off[n] = part[1023];
}

__global__ void scatter_kernel(const int* __restrict__ dst, const int* __restrict__ off,
                               int* __restrict__ cursor, int* __restrict__ csr, int E) {
  int tid = blockIdx.x * 256 + threadIdx.x;
  if (tid < E) {
    int d = dst[tid];
    int p = atomicAdd(&cursor[d], 1);
    csr[off[d] + p] = tid;
  }
}

// ---------------------------------------------------------------------------
// Node-type buckets — hierarchical (LDS / wave-aggregated) to avoid
// same-address device-atomic contention (4 counters x 20000 threads was
// 122 us; per-wave ballot aggregation cuts global atomics ~16-64x).
// ---------------------------------------------------------------------------
__global__ void tcount_kernel(const int* __restrict__ nt, int* __restrict__ tcnt, int N) {
  __shared__ int h[NTYPE];
  int t = threadIdx.x;
  if (t < NTYPE) h[t] = 0;
  __syncthreads();
  int tid = blockIdx.x * 256 + t;
  if (tid < N) atomicAdd(&h[nt[tid]], 1);
  __syncthreads();
  if (t < NTYPE && h[t] > 0) atomicAdd(&tcnt[t], h[t]);
}

__global__ void tscan_kernel(const int* __restrict__ tcnt, int* __restrict__ toff,
                             int* __restrict__ tile_off) {
  if (threadIdx.x == 0 && blockIdx.x == 0) {
    int o = 0, to = 0;
    for (int t = 0; t < NTYPE; ++t) {
      toff[t] = o; tile_off[t] = to;
      o += tcnt[t]; to += (tcnt[t] + 63) >> 6;
    }
    toff[NTYPE] = o; tile_off[NTYPE] = to;
  }
}

__global__ void tscatter_kernel(const int* __restrict__ nt, const int* __restrict__ toff,
                                int* __restrict__ tcur, int* __restrict__ tidx, int N) {
  int tid = blockIdx.x * 256 + threadIdx.x;
  int lane = threadIdx.x & 63;
  int ty = (tid < N) ? nt[tid] : -1;
  unsigned long long lt_mask = (lane == 63) ? 0x7FFFFFFFFFFFFFFFull
                                            : ((1ull << lane) - 1);
#pragma unroll
  for (int t4 = 0; t4 < NTYPE; ++t4) {
    unsigned long long mask = __ballot(ty == t4);
    if (mask == 0) continue;  // wave-uniform
    int first = __builtin_ctzll(mask);
    int cnt = __popcll(mask);
    int base = 0;
    if (lane == first) base = atomicAdd(&tcur[t4], cnt);
    base = __shfl(base, first, 64);
    if (ty == t4) {
      int rank = __popcll(mask & lt_mask);
      tidx[toff[t4] + base + rank] = tid;
    }
  }
}

// ---------------------------------------------------------------------------
// x fp32 -> bf16 mirror
// ---------------------------------------------------------------------------
__global__ void xconv_kernel(const float* __restrict__ x, u16* __restrict__ xb, int n4) {
  int i = blockIdx.x * 256 + threadIdx.x;
  if (i < n4) {
    float4 v = ((const float4*)x)[i];
    ushort4 o = { f2bf(v.x), f2bf(v.y), f2bf(v.z), f2bf(v.w) };
    ((ushort4*)xb)[i] = o;
  }
}

// ---------------------------------------------------------------------------
// Weight prep: per (l,type,head) build bf16 B-operand-layout [col][k] mats:
// mat0 = WQ^T, mat1 = WV^T, mat2..4 = (WK @ WE[et])^T
// ---------------------------------------------------------------------------
__global__ __launch_bounds__(256) void wprep_kernel(
    const float* __restrict__ W_Q, const float* __restrict__ W_K,
    const float* __restrict__ W_V, const float* __restrict__ W_E,
    u16* __restrict__ wqkvb) {
  int b = blockIdx.x;                    // ((l*NTYPE+t)*NHEAD+h)
  int h = b & 7, tt = (b >> 3) & 3, l = b >> 5;
  __shared__ float wk[1024];
  __shared__ float we[3][1024];
  int t = threadIdx.x;
  const float* WKp = W_K + (((size_t)l * NTYPE + tt) * NHEAD + h) * 1024;
  for (int i = t; i < 1024; i += 256) wk[i] = WKp[i];
  for (int et = 0; et < ETYPE; ++et) {
    const float* WEp = W_E + (((size_t)l * ETYPE + et) * NHEAD + h) * 1024;
    for (int i = t; i < 1024; i += 256) we[et][i] = WEp[i];
  }
  __syncthreads();
  const float* WQp = W_Q + (((size_t)l * NTYPE + tt) * NHEAD + h) * 1024;
  const float* WVp = W_V + (((size_t)l * NTYPE + tt) * NHEAD + h) * 1024;
  u16* out = wqkvb + (size_t)b * 5120;
  for (int i = t; i < 1024; i += 256) {
    int col = i >> 5, k = i & 31;
    out[i] = f2bf(WQp[k * 32 + col]);
    out[1024 + i] = f2bf(WVp[k * 32 + col]);
#pragma unroll
    for (int et = 0; et < ETYPE; ++et) {
      float a = 0.f;
#pragma unroll
      for (int d = 0; d < 32; ++d) a += wk[k * 32 + d] * we[et][d * 32 + col];
      out[(2 + et) * 1024 + i] = f2bf(a);
    }
  }
}

// ---------------------------------------------------------------------------
// QKV via MFMA over type buckets. Block = (64-node tile of one type) x head.
// ---------------------------------------------------------------------------
__global__ __launch_bounds__(256) void qkv_mfma(
    const u16* __restrict__ xb, const int* __restrict__ tidx,
    const int* __restrict__ toff, const int* __restrict__ tile_off,
    const u16* __restrict__ wqkvb_l,
    u16* __restrict__ Qb, u16* __restrict__ Vb, u16* __restrict__ Ktb) {
  __shared__ u16 smem[10240];
  int bx = blockIdx.x, h = blockIdx.y;
  if (bx >= tile_off[NTYPE]) return;
  int ty = 0;
  while (bx >= tile_off[ty + 1]) ++ty;
  int lt = bx - tile_off[ty];
  int base = toff[ty] + lt * 64;
  int cnt = min(64, toff[ty + 1] - toff[ty] - lt * 64);
  int t = threadIdx.x;
  {
    int row = t >> 2, q = t & 3;
    int node = tidx[base + min(row, cnt - 1)];
    *(uint4*)&smem[row * 32 + q * 8] =
        *(const uint4*)&xb[(size_t)node * 256 + h * 32 + q * 8];
  }
  const u16* wsrc = wqkvb_l + ((size_t)ty * NHEAD + h) * 5120;
  for (int c = t; c < 640; c += 256)
    *(uint4*)&smem[2048 + c * 8] = *(const uint4*)&wsrc[c * 8];
  __syncthreads();

  int lane = t & 63, w = t >> 6;
  int m = lane & 15, q = lane >> 4;
  bf16x8 af = *(const bf16x8*)&smem[(w * 16 + m) * 32 + q * 8];
  f32x4 acc[5][2];
#pragma unroll
  for (int mt = 0; mt < 5; ++mt)
#pragma unroll
    for (int c = 0; c < 2; ++c) {
      bf16x8 bf = *(const bf16x8*)&smem[2048 + mt * 1024 + (c * 16 + m) * 32 + q * 8];
      acc[mt][c] = __builtin_amdgcn_mfma_f32_16x16x32_bf16(af, bf, (f32x4){0.f, 0.f, 0.f, 0.f}, 0, 0, 0);
    }
  __syncthreads();
#pragma unroll
  for (int mt = 0; mt < 5; ++mt)
#pragma unroll
    for (int c = 0; c < 2; ++c)
#pragma unroll
      for (int r = 0; r < 4; ++r)
        smem[mt * 2048 + (w * 16 + q * 4 + r) * 32 + c * 16 + m] = f2bf(acc[mt][c][r]);
  __syncthreads();
  {
    int row = t >> 2, q4 = t & 3;
    if (row < cnt) {
      int node = tidx[base + row];
      *(uint4*)&Qb[(size_t)node * 256 + h * 32 + q4 * 8] =
          *(const uint4*)&smem[row * 32 + q4 * 8];
      *(uint4*)&Vb[(size_t)node * 256 + h * 32 + q4 * 8] =
          *(const uint4*)&smem[2048 + row * 32 + q4 * 8];
#pragma unroll
      for (int et = 0; et < ETYPE; ++et)
        *(uint4*)&Ktb[((size_t)node * ETYPE + et) * 256 + h * 32 + q4 * 8] =
            *(const uint4*)&smem[(2 + et) * 2048 + row * 32 + q4 * 8];
    }
  }
}

// ---------------------------------------------------------------------------
// Edge scores (bf16 operands, fp32 accumulate)
// ---------------------------------------------------------------------------
__global__ __launch_bounds__(256) void score_kernel(
    const int* __restrict__ src, const int* __restrict__ dst,
    const int* __restrict__ etype, const u16* __restrict__ Qb,
    const u16* __restrict__ Ktb, const float* __restrict__ mu,
    float* __restrict__ scores, int E) {
  int tid = blockIdx.x * 256 + threadIdx.x;
  if (tid >= E * NHEAD) return;
  int eid = tid >> 3, h = tid & 7;
  int s = src[eid], d = dst[eid], t = etype[eid];
  const bf16x8* q = (const bf16x8*)(Qb + (size_t)d * 256 + h * 32);
  const bf16x8* k = (const bf16x8*)(Ktb + ((size_t)s * ETYPE + t) * 256 + h * 32);
  float acc = 0.f;
#pragma unroll
  for (int i = 0; i < 4; ++i) {
    bf16x8 a = q[i], b = k[i];
#pragma unroll
    for (int j = 0; j < 8; ++j) acc += (float)a[j] * (float)b[j];
  }
  scores[tid] = acc * 0.17677669529663687f * mu[h * ETYPE + t];
}

// ---------------------------------------------------------------------------
// Segment softmax + weighted V aggregation -> bf16 agg
// ---------------------------------------------------------------------------
__global__ __launch_bounds__(256) void agg_kernel(
    const int* __restrict__ off, const int* __restrict__ csr,
    const int* __restrict__ src, const float* __restrict__ scores,
    const u16* __restrict__ Vb, u16* __restrict__ aggb) {
  int n = blockIdx.x;
  int t = threadIdx.x;
  int h = t >> 5, j = t & 31;
  int s0 = off[n], s1 = off[n + 1];
  float m = -1e9f;
  for (int k = s0 + j; k < s1; k += 32) {
    int e = csr[k];
    m = fmaxf(m, scores[(size_t)e * 8 + h]);
  }
  for (int o = 16; o > 0; o >>= 1) m = fmaxf(m, __shfl_xor(m, o, 32));
  float ssum = 0.f;
  for (int k = s0 + j; k < s1; k += 32) {
    int e = csr[k];
    ssum += expf(scores[(size_t)e * 8 + h] - m);
  }
  for (int o = 16; o > 0; o >>= 1) ssum += __shfl_xor(ssum, o, 32);
  float inv = 1.f / (ssum + 1e-10f);
  float acc = 0.f;
  for (int k = s0; k < s1; ++k) {
    int e = csr[k];
    float w = expf(scores[(size_t)e * 8 + h] - m) * inv;
    int sn = src[e];
    acc += w * (float)*(const __bf16*)&Vb[(size_t)sn * 256 + h * 32 + j];
  }
  aggb[(size_t)n * 256 + t] = f2bf(acc);
}

// ---------------------------------------------------------------------------
// fp32 [K,Nc] -> bf16 transposed [Nc,K]
// ---------------------------------------------------------------------------
__global__ __launch_bounds__(256) void convT_kernel(const float* __restrict__ W,
                                                    u16* __restrict__ Wt, int K, int Nc) {
  __shared__ float tile[32][33];
  int bk = blockIdx.y * 32, bn = blockIdx.x * 32;
  const float* Wz = W + (size_t)blockIdx.z * K * Nc;
  u16* Wtz = Wt + (size_t)blockIdx.z * K * Nc;
  int tx = threadIdx.x & 31, ty = threadIdx.x >> 5;
  for (int r = ty; r < 32; r += 8)
    tile[r][tx] = Wz[(size_t)(bk + r) * Nc + bn + tx];
  __syncthreads();
  for (int r = ty; r < 32; r += 8)
    Wtz[(size_t)(bn + r) * K + bk + tx] = f2bf(tile[tx][r]);
}

// ---------------------------------------------------------------------------
// bf16 MFMA GEMM (m97 structure): C[M,Nc] = A[M,K] @ Bt[Nc,K]^T + bias
// ---------------------------------------------------------------------------
template <int EPI>  // 0: fp32 out + bias; 1: bf16 out + bias + exact GELU
__global__ __launch_bounds__(256) void gemm_mfma(
    const u16* __restrict__ A, const u16* __restrict__ Bt,
    const float* __restrict__ bias, float* __restrict__ Cf,
    u16* __restrict__ Cb, int M, int K, int Nc) {
  __shared__ u16 As[128 * 32];
  __shared__ u16 Bs[128 * 32];
  const int t = threadIdx.x;
  const int lane = t & 63;
  const int w = t >> 6;
  const int row0 = blockIdx.y * 128;
  const int col0 = blockIdx.x * 128;
  const int wm = (w >> 1) * 64, wn = (w & 1) * 64;

  f32x4 acc[4][4] = {};
  const int sr = lane >> 2;
  const int sk = (lane & 3) * 8;

  for (int k0 = 0; k0 < K; k0 += 32) {
#pragma unroll
    for (int c = 0; c < 2; ++c) {
      const int chunk = w * 2 + c;
      const int r = chunk * 16 + sr;
      int ra = row0 + r; if (ra >= M) ra = M - 1;
      GLDS16(A + (size_t)ra * K + k0 + sk, &As[(chunk * 64 + lane) * 8]);
      GLDS16(Bt + (size_t)(col0 + r) * K + k0 + sk, &Bs[(chunk * 64 + lane) * 8]);
    }
    __syncthreads();
    bf16x8 af[4], bfr[4];
    const int ko = (lane >> 4) * 8;
    const int lr = lane & 15;
#pragma unroll
    for (int i = 0; i < 4; ++i)
      af[i] = *(const bf16x8*)&As[(wm + i * 16 + lr) * 32 + ko];
#pragma unroll
    for (int j = 0; j < 4; ++j)
      bfr[j] = *(const bf16x8*)&Bs[(wn + j * 16 + lr) * 32 + ko];
#pragma unroll
    for (int i = 0; i < 4; ++i)
#pragma unroll
      for (int j = 0; j < 4; ++j)
        acc[i][j] = __builtin_amdgcn_mfma_f32_16x16x32_bf16(af[i], bfr[j], acc[i][j], 0, 0, 0);
    __syncthreads();
  }

  const int lc = lane & 15;
  const int lrow = (lane >> 4) * 4;
#pragma unroll
  for (int i = 0; i < 4; ++i) {
#pragma unroll
    for (int r = 0; r < 4; ++r) {
      int gr = row0 + wm + i * 16 + lrow + r;
      if (gr >= M) continue;
#pragma unroll
      for (int j = 0; j < 4; ++j) {
        int gc = col0 + wn + j * 16 + lc;
        float v = acc[i][j][r] + bias[gc];
        if (EPI == 1) {
          v = 0.5f * v * (1.f + erff(v * 0.70710678118654752f));
          Cb[(size_t)gr * Nc + gc] = f2bf(v);
        } else {
          Cf[(size_t)gr * Nc + gc] = v;
        }
      }
    }
  }
}

// ---------------------------------------------------------------------------
// LayerNorm rows of 256: out = LN(xin + res) * g + b; optional bf16 mirror
// ---------------------------------------------------------------------------
__global__ __launch_bounds__(256) void ln_kernel(
    const float* __restrict__ xin, const float* __restrict__ res,
    const float* __restrict__ g, const float* __restrict__ b,
    float* __restrict__ out, u16* __restrict__ outb) {
  int n = blockIdx.x;
  int t = threadIdx.x;
  __shared__ float red[8];
  size_t idx = (size_t)n * 256 + t;
  float r = xin[idx] + (res ? res[idx] : 0.f);
  float s = r;
  for (int o = 32; o > 0; o >>= 1) s += __shfl_xor(s, o, 64);
  if ((t & 63) == 0) red[t >> 6] = s;
  __syncthreads();
  float m = (red[0] + red[1] + red[2] + red[3]) * (1.f / 256.f);
  float d = r - m;
  float s2 = d * d;
  for (int o = 32; o > 0; o >>= 1) s2 += __shfl_xor(s2, o, 64);
  if ((t & 63) == 0) red[4 + (t >> 6)] = s2;
  __syncthreads();
  float var = (red[4] + red[5] + red[6] + red[7]) * (1.f / 256.f);
  float o = d * rsqrtf(var + 1e-5f) * g[t] + b[t];
  out[idx] = o;
  if (outb) outb[idx] = f2bf(o);
}

// ---------------------------------------------------------------------------
extern "C" void kernel_launch(void* const* d_in, const int* in_sizes, int n_in,
                              void* d_out, int out_size, void* d_ws, size_t ws_size,
                              hipStream_t stream) {
  const float* x_in   = (const float*)d_in[0];
  const int*   ei     = (const int*)d_in[1];
  const int*   etype  = (const int*)d_in[2];
  const int*   ntype  = (const int*)d_in[3];
  const float* W_Q    = (const float*)d_in[4];
  const float* W_K    = (const float*)d_in[5];
  const float* W_V    = (const float*)d_in[6];
  const float* W_E    = (const float*)d_in[7];
  const float* mu     = (const float*)d_in[8];
  const float* Wo     = (const float*)d_in[9];
  const float* bo     = (const float*)d_in[10];
  const float* ln1g   = (const float*)d_in[11];
  const float* ln1b   = (const float*)d_in[12];
  const float* ln2g   = (const float*)d_in[13];
  const float* ln2b   = (const float*)d_in[14];
  const float* w1     = (const float*)d_in[15];
  const float* b1     = (const float*)d_in[16];
  const float* w2     = (const float*)d_in[17];
  const float* b2     = (const float*)d_in[18];
  const float* outg   = (const float*)d_in[19];
  const float* outb   = (const float*)d_in[20];

  const int N = in_sizes[0] / DMODEL;    // 20000
  const int E = in_sizes[1] / 2;         // 320000
  const int* src = ei;
  const int* dst = ei + E;

  const size_t NF = (size_t)N * DMODEL;
  const size_t EH = (size_t)E * NHEAD;

  // ---- workspace layout ----
  float* f      = (float*)d_ws;
  float* xbuf   = f;                     // NF fp32 (LN residual master)
  float* fout   = f + NF;                // NF fp32 (GEMM fp32 outputs)
  float* scores = f + 2 * NF;            // EH fp32
  u16*   xb     = (u16*)(f + 2 * NF + EH);  // NF bf16 mirror of x
  u16*   Qb     = xb + NF;               // NF
  u16*   Vb     = Qb + NF;               // NF   } h1b aliases Vb..Ktb
  u16*   Ktb    = Vb + NF;               // 3NF  }
  u16*   h1b    = Vb;                    // alias
  u16*   aggb   = Ktb + 3 * NF;          // NF
  u16*   wqkvb  = aggb + NF;             // 96 * 5120
  u16*   Wot    = wqkvb + (size_t)NLAYER * NTYPE * NHEAD * 5120;
  u16*   w1t    = Wot + 3 * 65536;
  u16*   w2t    = w1t + 3 * 262144;
  int*   ip     = (int*)(w2t + 3 * 262144);
  int*   off    = ip;                    // N+1
  int*   csr    = off + (N + 1);         // E
  int*   cursor = csr + E;               // N (deg, then cursor)
  int*   tidx   = cursor + N;            // N
  int*   toff   = tidx + N;              // NTYPE+1
  int*   tile_off = toff + (NTYPE + 1);  // NTYPE+1
  int*   tcnt   = tile_off + (NTYPE + 1);// NTYPE
  int*   tcur   = tcnt + NTYPE;          // NTYPE

  // ---- CSR + type buckets (once) ----
  hipMemsetAsync(cursor, 0, (size_t)N * sizeof(int), stream);
  hipMemsetAsync(tcnt, 0, 2 * NTYPE * sizeof(int), stream);
  count_deg_kernel<<<(E + 255) / 256, 256, 0, stream>>>(dst, cursor, E);
  scan_kernel<<<1, 1024, 0, stream>>>(cursor, off, N);
  hipMemsetAsync(cursor, 0, (size_t)N * sizeof(int), stream);
  scatter_kernel<<<(E + 255) / 256, 256, 0, stream>>>(dst, off, cursor, csr, E);
  tcount_kernel<<<(N + 255) / 256, 256, 0, stream>>>(ntype, tcnt, N);
  tscan_kernel<<<1, 64, 0, stream>>>(tcnt, toff, tile_off);
  tscatter_kernel<<<(N + 255) / 256, 256, 0, stream>>>(ntype, toff, tcur, tidx, N);

  // ---- weight prep (once) ----
  wprep_kernel<<<NLAYER * NTYPE * NHEAD, 256, 0, stream>>>(W_Q, W_K, W_V, W_E, wqkvb);
  convT_kernel<<<dim3(DMODEL / 32, DMODEL / 32, NLAYER), 256, 0, stream>>>(
      Wo, Wot, DMODEL, DMODEL);
  convT_kernel<<<dim3(4 * DMODEL / 32, DMODEL / 32, NLAYER), 256, 0, stream>>>(
      w1, w1t, DMODEL, 4 * DMODEL);
  convT_kernel<<<dim3(DMODEL / 32, 4 * DMODEL / 32, NLAYER), 256, 0, stream>>>(
      w2, w2t, 4 * DMODEL, DMODEL);

  // ---- x working copies ----
  hipMemcpyAsync(xbuf, x_in, NF * sizeof(float), hipMemcpyDeviceToDevice, stream);
  xconv_kernel<<<(int)((NF / 4 + 255) / 256), 256, 0, stream>>>(x_in, xb, (int)(NF / 4));

  const int gm = (N + 127) / 128;
  const int qtiles = (N + 63) / 64 + NTYPE;
  for (int l = 0; l < NLAYER; ++l) {
    qkv_mfma<<<dim3(qtiles, NHEAD), 256, 0, stream>>>(
        xb, tidx, toff, tile_off,
        wqkvb + (size_t)l * NTYPE * NHEAD * 5120, Qb, Vb, Ktb);
    score_kernel<<<(int)((EH + 255) / 256), 256, 0, stream>>>(
        src, dst, etype, Qb, Ktb, mu + (size_t)l * NHEAD * ETYPE, scores, E);
    agg_kernel<<<N, 256, 0, stream>>>(off, csr, src, scores, Vb, aggb);

    gemm_mfma<0><<<dim3(DMODEL / 128, gm), 256, 0, stream>>>(
        aggb, Wot + (size_t)l * 65536, bo + (size_t)l * DMODEL,
        fout, nullptr, N, DMODEL, DMODEL);
    ln_kernel<<<N, 256, 0, stream>>>(xbuf, fout,
        ln1g + (size_t)l * DMODEL, ln1b + (size_t)l * DMODEL, xbuf, xb);
    gemm_mfma<1><<<dim3(4 * DMODEL / 128, gm), 256, 0, stream>>>(
        xb, w1t + (size_t)l * 262144, b1 + (size_t)l * 4 * DMODEL,
        nullptr, h1b, N, DMODEL, 4 * DMODEL);
    gemm_mfma<0><<<dim3(DMODEL / 128, gm), 256, 0, stream>>>(
        h1b, w2t + (size_t)l * 262144, b2 + (size_t)l * DMODEL,
        fout, nullptr, N, 4 * DMODEL, DMODEL);
    ln_kernel<<<N, 256, 0, stream>>>(xbuf, fout,
        ln2g + (size_t)l * DMODEL, ln2b + (size_t)l * DMODEL, xbuf, xb);
  }

  ln_kernel<<<N, 256, 0, stream>>>(xbuf, nullptr, outg, outb, (float*)d_out, nullptr);
}

// Round 5
// 945.956 us; speedup vs baseline: 2.4821x; 1.2324x over previous
//
#include <hip/hip_runtime.h>
#include <math.h>

#define HDIM 32
#define NHEAD 8
#define DMODEL 256
#define NTYPE 4
#define ETYPE 3
#define NLAYER 3

typedef unsigned short u16;
typedef __bf16 bf16x8 __attribute__((ext_vector_type(8)));
typedef float f32x4 __attribute__((ext_vector_type(4)));

__device__ __forceinline__ u16 f2bf(float f) {
  union { float f; unsigned u; } v; v.f = f;
  unsigned r = v.u + 0x7FFF + ((v.u >> 16) & 1);
  return (u16)(r >> 16);
}

#define GLDS16(g, l)                                              \
  __builtin_amdgcn_global_load_lds(                               \
      (const __attribute__((address_space(1))) void*)(g),         \
      (__attribute__((address_space(3))) void*)(l), 16, 0, 0)

// ---------------------------------------------------------------------------
// CSR build (dst-sorted edge VALUES: src/dst/etype materialized in position
// order so all downstream access is sequential — avoids per-XCD L2
// replication of random edge-id gathers)
// ---------------------------------------------------------------------------
__global__ void count_deg_kernel(const int* __restrict__ dst, int* __restrict__ deg, int E) {
  int tid = blockIdx.x * 256 + threadIdx.x;
  if (tid < E) atomicAdd(&deg[dst[tid]], 1);
}

__global__ __launch_bounds__(1024) void scan_kernel(const int* __restrict__ deg,
                                                    int* __restrict__ off, int n) {
  __shared__ int part[1024];
  int t = threadIdx.x;
  int chunk = (n + 1023) >> 10;
  int base = t * chunk;
  int s = 0;
  for (int i = 0; i < chunk; ++i) {
    int idx = base + i;
    if (idx < n) s += deg[idx];
  }
  part[t] = s;
  __syncthreads();
  for (int o = 1; o < 1024; o <<= 1) {
    int v = (t >= o) ? part[t - o] : 0;
    __syncthreads();
    part[t] += v;
    __syncthreads();
  }
  int run = part[t] - s;
  for (int i = 0; i < chunk; ++i) {
    int idx = base + i;
    if (idx < n) { off[idx] = run; run += deg[idx]; }
  }
  if (t == 1023) off[n] = part[1023];
}

__global__ void scatter_kernel(const int* __restrict__ src, const int* __restrict__ dst,
                               const int* __restrict__ etype,
                               const int* __restrict__ off, int* __restrict__ cursor,
                               int* __restrict__ csr_src, int* __restrict__ csr_dst,
                               int* __restrict__ csr_et, int E) {
  int tid = blockIdx.x * 256 + threadIdx.x;
  if (tid < E) {
    int d = dst[tid];
    int p = atomicAdd(&cursor[d], 1);
    int pos = off[d] + p;
    csr_src[pos] = src[tid];
    csr_dst[pos] = d;
    csr_et[pos] = etype[tid];
  }
}

// ---------------------------------------------------------------------------
// Node-type buckets — hierarchical to avoid same-address atomic contention
// ---------------------------------------------------------------------------
__global__ void tcount_kernel(const int* __restrict__ nt, int* __restrict__ tcnt, int N) {
  __shared__ int h[NTYPE];
  int t = threadIdx.x;
  if (t < NTYPE) h[t] = 0;
  __syncthreads();
  int tid = blockIdx.x * 256 + t;
  if (tid < N) atomicAdd(&h[nt[tid]], 1);
  __syncthreads();
  if (t < NTYPE && h[t] > 0) atomicAdd(&tcnt[t], h[t]);
}

__global__ void tscan_kernel(const int* __restrict__ tcnt, int* __restrict__ toff,
                             int* __restrict__ tile_off) {
  if (threadIdx.x == 0 && blockIdx.x == 0) {
    int o = 0, to = 0;
    for (int t = 0; t < NTYPE; ++t) {
      toff[t] = o; tile_off[t] = to;
      o += tcnt[t]; to += (tcnt[t] + 63) >> 6;
    }
    toff[NTYPE] = o; tile_off[NTYPE] = to;
  }
}

__global__ void tscatter_kernel(const int* __restrict__ nt, const int* __restrict__ toff,
                                int* __restrict__ tcur, int* __restrict__ tidx, int N) {
  int tid = blockIdx.x * 256 + threadIdx.x;
  int lane = threadIdx.x & 63;
  int ty = (tid < N) ? nt[tid] : -1;
  unsigned long long lt_mask = (lane == 63) ? 0x7FFFFFFFFFFFFFFFull
                                            : ((1ull << lane) - 1);
#pragma unroll
  for (int t4 = 0; t4 < NTYPE; ++t4) {
    unsigned long long mask = __ballot(ty == t4);
    if (mask == 0) continue;
    int first = __builtin_ctzll(mask);
    int cnt = __popcll(mask);
    int base = 0;
    if (lane == first) base = atomicAdd(&tcur[t4], cnt);
    base = __shfl(base, first, 64);
    if (ty == t4) {
      int rank = __popcll(mask & lt_mask);
      tidx[toff[t4] + base + rank] = tid;
    }
  }
}

// ---------------------------------------------------------------------------
// x fp32 -> bf16 mirror
// ---------------------------------------------------------------------------
__global__ void xconv_kernel(const float* __restrict__ x, u16* __restrict__ xb, int n4) {
  int i = blockIdx.x * 256 + threadIdx.x;
  if (i < n4) {
    float4 v = ((const float4*)x)[i];
    ushort4 o = { f2bf(v.x), f2bf(v.y), f2bf(v.z), f2bf(v.w) };
    ((ushort4*)xb)[i] = o;
  }
}

// ---------------------------------------------------------------------------
// Weight prep: per (l,type,head) bf16 B-operand mats: WQ^T, WV^T, (WK@WE[et])^T
// ---------------------------------------------------------------------------
__global__ __launch_bounds__(256) void wprep_kernel(
    const float* __restrict__ W_Q, const float* __restrict__ W_K,
    const float* __restrict__ W_V, const float* __restrict__ W_E,
    u16* __restrict__ wqkvb) {
  int b = blockIdx.x;
  int h = b & 7, tt = (b >> 3) & 3, l = b >> 5;
  __shared__ float wk[1024];
  __shared__ float we[3][1024];
  int t = threadIdx.x;
  const float* WKp = W_K + (((size_t)l * NTYPE + tt) * NHEAD + h) * 1024;
  for (int i = t; i < 1024; i += 256) wk[i] = WKp[i];
  for (int et = 0; et < ETYPE; ++et) {
    const float* WEp = W_E + (((size_t)l * ETYPE + et) * NHEAD + h) * 1024;
    for (int i = t; i < 1024; i += 256) we[et][i] = WEp[i];
  }
  __syncthreads();
  const float* WQp = W_Q + (((size_t)l * NTYPE + tt) * NHEAD + h) * 1024;
  const float* WVp = W_V + (((size_t)l * NTYPE + tt) * NHEAD + h) * 1024;
  u16* out = wqkvb + (size_t)b * 5120;
  for (int i = t; i < 1024; i += 256) {
    int col = i >> 5, k = i & 31;
    out[i] = f2bf(WQp[k * 32 + col]);
    out[1024 + i] = f2bf(WVp[k * 32 + col]);
#pragma unroll
    for (int et = 0; et < ETYPE; ++et) {
      float a = 0.f;
#pragma unroll
      for (int d = 0; d < 32; ++d) a += wk[k * 32 + d] * we[et][d * 32 + col];
      out[(2 + et) * 1024 + i] = f2bf(a);
    }
  }
}

// ---------------------------------------------------------------------------
// QKV via MFMA over type buckets
// ---------------------------------------------------------------------------
__global__ __launch_bounds__(256) void qkv_mfma(
    const u16* __restrict__ xb, const int* __restrict__ tidx,
    const int* __restrict__ toff, const int* __restrict__ tile_off,
    const u16* __restrict__ wqkvb_l,
    u16* __restrict__ Qb, u16* __restrict__ Vb, u16* __restrict__ Ktb) {
  __shared__ u16 smem[10240];
  int bx = blockIdx.x, h = blockIdx.y;
  if (bx >= tile_off[NTYPE]) return;
  int ty = 0;
  while (bx >= tile_off[ty + 1]) ++ty;
  int lt = bx - tile_off[ty];
  int base = toff[ty] + lt * 64;
  int cnt = min(64, toff[ty + 1] - toff[ty] - lt * 64);
  int t = threadIdx.x;
  {
    int row = t >> 2, q = t & 3;
    int node = tidx[base + min(row, cnt - 1)];
    *(uint4*)&smem[row * 32 + q * 8] =
        *(const uint4*)&xb[(size_t)node * 256 + h * 32 + q * 8];
  }
  const u16* wsrc = wqkvb_l + ((size_t)ty * NHEAD + h) * 5120;
  for (int c = t; c < 640; c += 256)
    *(uint4*)&smem[2048 + c * 8] = *(const uint4*)&wsrc[c * 8];
  __syncthreads();

  int lane = t & 63, w = t >> 6;
  int m = lane & 15, q = lane >> 4;
  bf16x8 af = *(const bf16x8*)&smem[(w * 16 + m) * 32 + q * 8];
  f32x4 acc[5][2];
#pragma unroll
  for (int mt = 0; mt < 5; ++mt)
#pragma unroll
    for (int c = 0; c < 2; ++c) {
      bf16x8 bf = *(const bf16x8*)&smem[2048 + mt * 1024 + (c * 16 + m) * 32 + q * 8];
      acc[mt][c] = __builtin_amdgcn_mfma_f32_16x16x32_bf16(af, bf, (f32x4){0.f, 0.f, 0.f, 0.f}, 0, 0, 0);
    }
  __syncthreads();
#pragma unroll
  for (int mt = 0; mt < 5; ++mt)
#pragma unroll
    for (int c = 0; c < 2; ++c)
#pragma unroll
      for (int r = 0; r < 4; ++r)
        smem[mt * 2048 + (w * 16 + q * 4 + r) * 32 + c * 16 + m] = f2bf(acc[mt][c][r]);
  __syncthreads();
  {
    int row = t >> 2, q4 = t & 3;
    if (row < cnt) {
      int node = tidx[base + row];
      *(uint4*)&Qb[(size_t)node * 256 + h * 32 + q4 * 8] =
          *(const uint4*)&smem[row * 32 + q4 * 8];
      *(uint4*)&Vb[(size_t)node * 256 + h * 32 + q4 * 8] =
          *(const uint4*)&smem[2048 + row * 32 + q4 * 8];
#pragma unroll
      for (int et = 0; et < ETYPE; ++et)
        *(uint4*)&Ktb[((size_t)node * ETYPE + et) * 256 + h * 32 + q4 * 8] =
            *(const uint4*)&smem[(2 + et) * 2048 + row * 32 + q4 * 8];
    }
  }
}

// ---------------------------------------------------------------------------
// Edge scores, position-parallel over the dst-sorted CSR: coalesced csr
// reads, dst-run locality on the Q gather, fully coalesced score writes.
// ---------------------------------------------------------------------------
__global__ __launch_bounds__(256) void score_kernel(
    const int* __restrict__ csr_src, const int* __restrict__ csr_dst,
    const int* __restrict__ csr_et, const u16* __restrict__ Qb,
    const u16* __restrict__ Ktb, const float* __restrict__ mu,
    float* __restrict__ scores, int E) {
  int tid = blockIdx.x * 256 + threadIdx.x;
  if (tid >= E * NHEAD) return;
  int p = tid >> 3, h = tid & 7;
  int s = csr_src[p], d = csr_dst[p], t = csr_et[p];
  const bf16x8* q = (const bf16x8*)(Qb + (size_t)d * 256 + h * 32);
  const bf16x8* k = (const bf16x8*)(Ktb + ((size_t)s * ETYPE + t) * 256 + h * 32);
  float acc = 0.f;
#pragma unroll
  for (int i = 0; i < 4; ++i) {
    bf16x8 a = q[i], b = k[i];
#pragma unroll
    for (int j = 0; j < 8; ++j) acc += (float)a[j] * (float)b[j];
  }
  scores[tid] = acc * 0.17677669529663687f * mu[h * ETYPE + t];
}

// ---------------------------------------------------------------------------
// Segment softmax + weighted V aggregation. scores are segment-sequential;
// phase 2 stores exp(s-m) back in place (segment is block-owned), phase 3 is
// a pure fma loop with inv folded at the end.
// ---------------------------------------------------------------------------
__global__ __launch_bounds__(256) void agg_kernel(
    const int* __restrict__ off, const int* __restrict__ csr_src,
    float* __restrict__ scores, const u16* __restrict__ Vb,
    u16* __restrict__ aggb) {
  int n = blockIdx.x;
  int t = threadIdx.x;
  int h = t >> 5, j = t & 31;
  int s0 = off[n], s1 = off[n + 1];
  float m = -1e9f;
  for (int k = s0 + j; k < s1; k += 32)
    m = fmaxf(m, scores[(size_t)k * 8 + h]);
  for (int o = 16; o > 0; o >>= 1) m = fmaxf(m, __shfl_xor(m, o, 32));
  float ssum = 0.f;
  for (int k = s0 + j; k < s1; k += 32) {
    float ev = expf(scores[(size_t)k * 8 + h] - m);
    scores[(size_t)k * 8 + h] = ev;
    ssum += ev;
  }
  for (int o = 16; o > 0; o >>= 1) ssum += __shfl_xor(ssum, o, 32);
  float inv = 1.f / (ssum + 1e-10f);
  float acc = 0.f;
  int k = s0;
  for (; k + 1 < s1; k += 2) {
    float w0 = scores[(size_t)k * 8 + h];
    float w1 = scores[(size_t)(k + 1) * 8 + h];
    int sn0 = csr_src[k], sn1 = csr_src[k + 1];
    float v0 = (float)*(const __bf16*)&Vb[(size_t)sn0 * 256 + h * 32 + j];
    float v1 = (float)*(const __bf16*)&Vb[(size_t)sn1 * 256 + h * 32 + j];
    acc += w0 * v0 + w1 * v1;
  }
  if (k < s1) {
    float w0 = scores[(size_t)k * 8 + h];
    int sn0 = csr_src[k];
    acc += w0 * (float)*(const __bf16*)&Vb[(size_t)sn0 * 256 + h * 32 + j];
  }
  aggb[(size_t)n * 256 + t] = f2bf(acc * inv);
}

// ---------------------------------------------------------------------------
// fp32 [K,Nc] -> bf16 transposed [Nc,K]
// ---------------------------------------------------------------------------
__global__ __launch_bounds__(256) void convT_kernel(const float* __restrict__ W,
                                                    u16* __restrict__ Wt, int K, int Nc) {
  __shared__ float tile[32][33];
  int bk = blockIdx.y * 32, bn = blockIdx.x * 32;
  const float* Wz = W + (size_t)blockIdx.z * K * Nc;
  u16* Wtz = Wt + (size_t)blockIdx.z * K * Nc;
  int tx = threadIdx.x & 31, ty = threadIdx.x >> 5;
  for (int r = ty; r < 32; r += 8)
    tile[r][tx] = Wz[(size_t)(bk + r) * Nc + bn + tx];
  __syncthreads();
  for (int r = ty; r < 32; r += 8)
    Wtz[(size_t)(bn + r) * K + bk + tx] = f2bf(tile[tx][r]);
}

// ---------------------------------------------------------------------------
// bf16 MFMA GEMM (m97 structure): C[M,Nc] = A[M,K] @ Bt[Nc,K]^T + bias
// ---------------------------------------------------------------------------
template <int EPI>  // 0: fp32 out + bias; 1: bf16 out + bias + exact GELU
__global__ __launch_bounds__(256) void gemm_mfma(
    const u16* __restrict__ A, const u16* __restrict__ Bt,
    const float* __restrict__ bias, float* __restrict__ Cf,
    u16* __restrict__ Cb, int M, int K, int Nc) {
  __shared__ u16 As[128 * 32];
  __shared__ u16 Bs[128 * 32];
  const int t = threadIdx.x;
  const int lane = t & 63;
  const int w = t >> 6;
  const int row0 = blockIdx.y * 128;
  const int col0 = blockIdx.x * 128;
  const int wm = (w >> 1) * 64, wn = (w & 1) * 64;

  f32x4 acc[4][4] = {};
  const int sr = lane >> 2;
  const int sk = (lane & 3) * 8;

  for (int k0 = 0; k0 < K; k0 += 32) {
#pragma unroll
    for (int c = 0; c < 2; ++c) {
      const int chunk = w * 2 + c;
      const int r = chunk * 16 + sr;
      int ra = row0 + r; if (ra >= M) ra = M - 1;
      GLDS16(A + (size_t)ra * K + k0 + sk, &As[(chunk * 64 + lane) * 8]);
      GLDS16(Bt + (size_t)(col0 + r) * K + k0 + sk, &Bs[(chunk * 64 + lane) * 8]);
    }
    __syncthreads();
    bf16x8 af[4], bfr[4];
    const int ko = (lane >> 4) * 8;
    const int lr = lane & 15;
#pragma unroll
    for (int i = 0; i < 4; ++i)
      af[i] = *(const bf16x8*)&As[(wm + i * 16 + lr) * 32 + ko];
#pragma unroll
    for (int j = 0; j < 4; ++j)
      bfr[j] = *(const bf16x8*)&Bs[(wn + j * 16 + lr) * 32 + ko];
#pragma unroll
    for (int i = 0; i < 4; ++i)
#pragma unroll
      for (int j = 0; j < 4; ++j)
        acc[i][j] = __builtin_amdgcn_mfma_f32_16x16x32_bf16(af[i], bfr[j], acc[i][j], 0, 0, 0);
    __syncthreads();
  }

  const int lc = lane & 15;
  const int lrow = (lane >> 4) * 4;
#pragma unroll
  for (int i = 0; i < 4; ++i) {
#pragma unroll
    for (int r = 0; r < 4; ++r) {
      int gr = row0 + wm + i * 16 + lrow + r;
      if (gr >= M) continue;
#pragma unroll
      for (int j = 0; j < 4; ++j) {
        int gc = col0 + wn + j * 16 + lc;
        float v = acc[i][j][r] + bias[gc];
        if (EPI == 1) {
          v = 0.5f * v * (1.f + erff(v * 0.70710678118654752f));
          Cb[(size_t)gr * Nc + gc] = f2bf(v);
        } else {
          Cf[(size_t)gr * Nc + gc] = v;
        }
      }
    }
  }
}

// ---------------------------------------------------------------------------
// LayerNorm rows of 256: out = LN(xin + res) * g + b; optional bf16 mirror
// ---------------------------------------------------------------------------
__global__ __launch_bounds__(256) void ln_kernel(
    const float* __restrict__ xin, const float* __restrict__ res,
    const float* __restrict__ g, const float* __restrict__ b,
    float* __restrict__ out, u16* __restrict__ outb) {
  int n = blockIdx.x;
  int t = threadIdx.x;
  __shared__ float red[8];
  size_t idx = (size_t)n * 256 + t;
  float r = xin[idx] + (res ? res[idx] : 0.f);
  float s = r;
  for (int o = 32; o > 0; o >>= 1) s += __shfl_xor(s, o, 64);
  if ((t & 63) == 0) red[t >> 6] = s;
  __syncthreads();
  float m = (red[0] + red[1] + red[2] + red[3]) * (1.f / 256.f);
  float d = r - m;
  float s2 = d * d;
  for (int o = 32; o > 0; o >>= 1) s2 += __shfl_xor(s2, o, 64);
  if ((t & 63) == 0) red[4 + (t >> 6)] = s2;
  __syncthreads();
  float var = (red[4] + red[5] + red[6] + red[7]) * (1.f / 256.f);
  float o = d * rsqrtf(var + 1e-5f) * g[t] + b[t];
  out[idx] = o;
  if (outb) outb[idx] = f2bf(o);
}

// ---------------------------------------------------------------------------
extern "C" void kernel_launch(void* const* d_in, const int* in_sizes, int n_in,
                              void* d_out, int out_size, void* d_ws, size_t ws_size,
                              hipStream_t stream) {
  const float* x_in   = (const float*)d_in[0];
  const int*   ei     = (const int*)d_in[1];
  const int*   etype  = (const int*)d_in[2];
  const int*   ntype  = (const int*)d_in[3];
  const float* W_Q    = (const float*)d_in[4];
  const float* W_K    = (const float*)d_in[5];
  const float* W_V    = (const float*)d_in[6];
  const float* W_E    = (const float*)d_in[7];
  const float* mu     = (const float*)d_in[8];
  const float* Wo     = (const float*)d_in[9];
  const float* bo     = (const float*)d_in[10];
  const float* ln1g   = (const float*)d_in[11];
  const float* ln1b   = (const float*)d_in[12];
  const float* ln2g   = (const float*)d_in[13];
  const float* ln2b   = (const float*)d_in[14];
  const float* w1     = (const float*)d_in[15];
  const float* b1     = (const float*)d_in[16];
  const float* w2     = (const float*)d_in[17];
  const float* b2     = (const float*)d_in[18];
  const float* outg   = (const float*)d_in[19];
  const float* outb   = (const float*)d_in[20];

  const int N = in_sizes[0] / DMODEL;    // 20000
  const int E = in_sizes[1] / 2;         // 320000
  const int* src = ei;
  const int* dst = ei + E;

  const size_t NF = (size_t)N * DMODEL;
  const size_t EH = (size_t)E * NHEAD;

  // ---- workspace layout ----
  float* f      = (float*)d_ws;
  float* xbuf   = f;                     // NF fp32
  float* fout   = f + NF;                // NF fp32
  float* scores = f + 2 * NF;            // EH fp32 (scratch: exp-weights in agg)
  u16*   xb     = (u16*)(f + 2 * NF + EH);
  u16*   Qb     = xb + NF;               // NF
  u16*   Vb     = Qb + NF;               // NF   } h1b aliases Vb..Ktb
  u16*   Ktb    = Vb + NF;               // 3NF  }
  u16*   h1b    = Vb;                    // alias
  u16*   aggb   = Ktb + 3 * NF;          // NF
  u16*   wqkvb  = aggb + NF;             // 96 * 5120
  u16*   Wot    = wqkvb + (size_t)NLAYER * NTYPE * NHEAD * 5120;
  u16*   w1t    = Wot + 3 * 65536;
  u16*   w2t    = w1t + 3 * 262144;
  int*   ip     = (int*)(w2t + 3 * 262144);
  int*   off    = ip;                    // N+1
  int*   csr_src= off + (N + 1);         // E
  int*   csr_dst= csr_src + E;           // E
  int*   csr_et = csr_dst + E;           // E
  int*   cursor = csr_et + E;            // N
  int*   tidx   = cursor + N;            // N
  int*   toff   = tidx + N;              // NTYPE+1
  int*   tile_off = toff + (NTYPE + 1);  // NTYPE+1
  int*   tcnt   = tile_off + (NTYPE + 1);// NTYPE
  int*   tcur   = tcnt + NTYPE;          // NTYPE

  // ---- CSR + type buckets (once) ----
  hipMemsetAsync(cursor, 0, (size_t)N * sizeof(int), stream);
  hipMemsetAsync(tcnt, 0, 2 * NTYPE * sizeof(int), stream);
  count_deg_kernel<<<(E + 255) / 256, 256, 0, stream>>>(dst, cursor, E);
  scan_kernel<<<1, 1024, 0, stream>>>(cursor, off, N);
  hipMemsetAsync(cursor, 0, (size_t)N * sizeof(int), stream);
  scatter_kernel<<<(E + 255) / 256, 256, 0, stream>>>(
      src, dst, etype, off, cursor, csr_src, csr_dst, csr_et, E);
  tcount_kernel<<<(N + 255) / 256, 256, 0, stream>>>(ntype, tcnt, N);
  tscan_kernel<<<1, 64, 0, stream>>>(tcnt, toff, tile_off);
  tscatter_kernel<<<(N + 255) / 256, 256, 0, stream>>>(ntype, toff, tcur, tidx, N);

  // ---- weight prep (once) ----
  wprep_kernel<<<NLAYER * NTYPE * NHEAD, 256, 0, stream>>>(W_Q, W_K, W_V, W_E, wqkvb);
  convT_kernel<<<dim3(DMODEL / 32, DMODEL / 32, NLAYER), 256, 0, stream>>>(
      Wo, Wot, DMODEL, DMODEL);
  convT_kernel<<<dim3(4 * DMODEL / 32, DMODEL / 32, NLAYER), 256, 0, stream>>>(
      w1, w1t, DMODEL, 4 * DMODEL);
  convT_kernel<<<dim3(DMODEL / 32, 4 * DMODEL / 32, NLAYER), 256, 0, stream>>>(
      w2, w2t, 4 * DMODEL, DMODEL);

  // ---- x working copies ----
  hipMemcpyAsync(xbuf, x_in, NF * sizeof(float), hipMemcpyDeviceToDevice, stream);
  xconv_kernel<<<(int)((NF / 4 + 255) / 256), 256, 0, stream>>>(x_in, xb, (int)(NF / 4));

  const int gm = (N + 127) / 128;
  const int qtiles = (N + 63) / 64 + NTYPE;
  for (int l = 0; l < NLAYER; ++l) {
    qkv_mfma<<<dim3(qtiles, NHEAD), 256, 0, stream>>>(
        xb, tidx, toff, tile_off,
        wqkvb + (size_t)l * NTYPE * NHEAD * 5120, Qb, Vb, Ktb);
    score_kernel<<<(int)((EH + 255) / 256), 256, 0, stream>>>(
        csr_src, csr_dst, csr_et, Qb, Ktb, mu + (size_t)l * NHEAD * ETYPE, scores, E);
    agg_kernel<<<N, 256, 0, stream>>>(off, csr_src, scores, Vb, aggb);

    gemm_mfma<0><<<dim3(DMODEL / 128, gm), 256, 0, stream>>>(
        aggb, Wot + (size_t)l * 65536, bo + (size_t)l * DMODEL,
        fout, nullptr, N, DMODEL, DMODEL);
    ln_kernel<<<N, 256, 0, stream>>>(xbuf, fout,
        ln1g + (size_t)l * DMODEL, ln1b + (size_t)l * DMODEL, xbuf, xb);
    gemm_mfma<1><<<dim3(4 * DMODEL / 128, gm), 256, 0, stream>>>(
        xb, w1t + (size_t)l * 262144, b1 + (size_t)l * 4 * DMODEL,
        nullptr, h1b, N, DMODEL, 4 * DMODEL);
    gemm_mfma<0><<<dim3(DMODEL / 128, gm), 256, 0, stream>>>(
        h1b, w2t + (size_t)l * 262144, b2 + (size_t)l * DMODEL,
        fout, nullptr, N, 4 * DMODEL, DMODEL);
    ln_kernel<<<N, 256, 0, stream>>>(xbuf, fout,
        ln2g + (size_t)l * DMODEL, ln2b + (size_t)l * DMODEL, xbuf, xb);
  }

  ln_kernel<<<N, 256, 0, stream>>>(xbuf, nullptr, outg, outb, (float*)d_out, nullptr);
}